// Round 2
// baseline (936.288 us; speedup 1.0000x reference)
//
#include <hip/hip_runtime.h>
#include <cstdint>
#include <cstddef>

namespace {

typedef unsigned short ushort_t;
typedef __attribute__((ext_vector_type(8))) short bf8v;   // 8 bf16 in 4 VGPR
typedef __attribute__((ext_vector_type(4))) float f4v;    // MFMA accumulator

constexpr float BNS = 0.99999500003749973f; // 1/sqrt(1+1e-5)

constexpr int TB = 32;      // T*B
constexpr int C  = 384;
constexpr int N  = 256;     // H*W
constexpr int ROWS = 868;   // 96 k + 384 v + 4 router + 384 q(E*ed)
constexpr int HID = 2048;
constexpr int HH  = 1024;

// workspace offsets (in floats)
constexpr size_t O_WPACK = 0;                       // 868*384 = 333312
constexpr size_t O_A1S = 333312;
constexpr size_t O_A1B = O_A1S + 868;
constexpr size_t O_APS = O_A1B + 868;
constexpr size_t O_APB = O_APS + 384;
constexpr size_t O_AHS = O_APB + 384;
constexpr size_t O_AHB = O_AHS + 2048;
constexpr size_t O_ADS = O_AHB + 2048;
constexpr size_t O_ADB = O_ADS + 1024;
constexpr size_t O_AFS = O_ADB + 1024;
constexpr size_t O_AFB = O_AFS + 384;               // ends 342728
constexpr size_t O_PRE  = 342784;                   // TB*ROWS*N fp32 = 7,110,656
constexpr size_t O_SPKB = 7453440;                  // bf16 spikes [tb][868][256] -> 3,555,328 floats
constexpr size_t O_QT   = 11008768;                 // bf16 [e*32+tb][256][96]    -> 1,572,864 floats
constexpr size_t O_KT   = 12581632;                 // bf16 [tb][256][96]         ->   393,216 floats
constexpr size_t O_ATTNB= 12974848;                 // bf16 [bi][256][256]        -> 4,194,304 floats
constexpr size_t O_RES  = 17169152;                 // fp32 [bi][256][384]        -> 12,582,912
constexpr size_t O_Y    = 11008768;                 // fp32 (over QT/KT, dead)     3,145,728
constexpr size_t O_PP   = 14154496;                 // fp32 (over ATTNB, dead)     3,145,728
constexpr size_t O_H    = 7453440;                  // fp32 16,777,216 (phase B)
constexpr size_t O_M    = 24230656;                 // fp32  8,388,608
constexpr size_t O_F2   = O_PRE;                    // fp32  3,145,728 (PRE dead)

// ---------------- pack weights + affines ----------------
__global__ __launch_bounds__(256) void pack_kernel(
    const float* __restrict__ kw, const float* __restrict__ vw,
    const float* __restrict__ rw, const float* __restrict__ rb,
    const float* __restrict__ rg, const float* __restrict__ rbe,
    const float* __restrict__ ew, const float* __restrict__ eg,
    const float* __restrict__ eb,
    float* __restrict__ WP, float* __restrict__ a1s, float* __restrict__ a1b)
{
  int u = blockIdx.x * 256 + threadIdx.x;
  if (u < ROWS * C) {
    int r = u / C, d = u % C;
    float w;
    if (r < 96)       w = kw[r * C + d];
    else if (r < 480) w = vw[(r - 96) * C + d];
    else if (r < 484) w = rw[(r - 480) * C + d];
    else              w = ew[(r - 484) * C + d];
    WP[u] = w;
  }
  if (u < ROWS) {
    float s, b;
    if (u < 480)      { s = 1.0f; b = 0.0f; }
    else if (u < 484) { int e = u - 480; s = rg[e] * BNS; b = rb[e] * rg[e] * BNS + rbe[e]; }
    else              { int j = u - 484; s = eg[j] * BNS; b = eb[j]; }
    a1s[u] = s; a1b[u] = b;
  }
}

__global__ __launch_bounds__(256) void aff_kernel(
    const float* __restrict__ g, const float* __restrict__ bias,
    const float* __restrict__ be, float* __restrict__ s, float* __restrict__ b, int n)
{
  int u = blockIdx.x * 256 + threadIdx.x;
  if (u < n) { s[u] = g[u] * BNS; b[u] = bias[u] * g[u] * BNS + be[u]; }
}

// ---------------- fp32 GEMM 128x128, 8x8/thread: OUT[b,o,n]=(sum_d W[o,d]X[b,d,n])*s[o]+b[o] ----
__global__ __launch_bounds__(256) void gemm2(
    const float* __restrict__ W, const float* __restrict__ X, float* __restrict__ OUT,
    const float* __restrict__ aS, const float* __restrict__ aB,
    int O, int D, long xStride, long oStride)
{
  __shared__ float Wt[16][132];
  __shared__ float Xt[16][132];
  const float* Xb = X + (size_t)blockIdx.z * xStride;
  float* Ob = OUT + (size_t)blockIdx.z * oStride;
  int n0 = blockIdx.x * 128, o0 = blockIdx.y * 128;
  int t = threadIdx.x, tx = t & 15, ty = t >> 4;
  float acc[8][8] = {};
  for (int kt = 0; kt < D; kt += 16) {
    int c = t & 15, r = t >> 4;
#pragma unroll
    for (int l = 0; l < 8; ++l) {
      int rr = r + 16 * l, orow = o0 + rr;
      Wt[c][rr] = (orow < O) ? W[(size_t)orow * D + kt + c] : 0.0f;
    }
#pragma unroll
    for (int l = 0; l < 8; ++l) {
      int idx = t + l * 256, r2 = idx >> 7, c2 = idx & 127;
      Xt[r2][c2] = Xb[(size_t)(kt + r2) * N + n0 + c2];
    }
    __syncthreads();
#pragma unroll
    for (int k = 0; k < 16; ++k) {
      float a[8], b[8];
#pragma unroll
      for (int i = 0; i < 4; ++i) { a[i] = Wt[k][ty * 4 + i]; a[i + 4] = Wt[k][64 + ty * 4 + i]; }
#pragma unroll
      for (int j = 0; j < 4; ++j) { b[j] = Xt[k][tx * 4 + j]; b[j + 4] = Xt[k][64 + tx * 4 + j]; }
#pragma unroll
      for (int i = 0; i < 8; ++i)
#pragma unroll
        for (int j = 0; j < 8; ++j) acc[i][j] += a[i] * b[j];
    }
    __syncthreads();
  }
#pragma unroll
  for (int i = 0; i < 8; ++i) {
    int orow = o0 + (i < 4 ? ty * 4 + i : 64 + ty * 4 + (i - 4));
    if (orow < O) {
      float s = aS[orow], bb = aB[orow];
#pragma unroll
      for (int j = 0; j < 8; ++j) {
        int col = n0 + (j < 4 ? tx * 4 + j : 64 + tx * 4 + (j - 4));
        Ob[(size_t)orow * N + col] = acc[i][j] * s + bb;
      }
    }
  }
}

// ---------------- LIF on PRE (in place) + bf16 spike copy ----------------
__global__ __launch_bounds__(256) void lif_pre(float* __restrict__ p, ushort_t* __restrict__ spkb)
{
  int j = blockIdx.x * 256 + threadIdx.x;
  int b = blockIdx.y;
  float mem = 0.0f;
#pragma unroll
  for (int t = 0; t < 4; ++t) {
    size_t idx = (size_t)(t * 8 + b) * ((size_t)ROWS * N) + j;
    float x = p[idx];
    mem += (x - mem) * 0.5f;
    bool fire = (mem >= 1.0f);
    p[idx] = fire ? 1.0f : 0.0f;
    spkb[idx] = fire ? (ushort_t)0x3F80 : (ushort_t)0;
    mem = fire ? 0.0f : mem;
  }
}

// ---------------- generic LIF (in place): p shape (nOuter, TB, FN) ----------------
__global__ __launch_bounds__(256) void lif_kernel(float* __restrict__ p, int FN)
{
  int j = blockIdx.x * 256 + threadIdx.x;
  int yb = blockIdx.y; int b = yb & 7; int e = yb >> 3;
  float mem = 0.0f;
#pragma unroll
  for (int t = 0; t < 4; ++t) {
    size_t idx = (size_t)(e * 32 + t * 8 + b) * FN + j;
    float x = p[idx];
    mem += (x - mem) * 0.5f;
    float sp = (mem >= 1.0f) ? 1.0f : 0.0f;
    p[idx] = sp;
    mem = (sp != 0.0f) ? 0.0f : mem;
  }
}

// ---------------- transpose spikes: SPKB[tb][base+ey*96+c][n] -> dst[ey*32+tb][n][c] ----------
__global__ __launch_bounds__(256) void transpose_spk(
    const ushort_t* __restrict__ SPKB, ushort_t* __restrict__ dst, int srcBase)
{
  __shared__ ushort_t tile[32][33];
  int z = blockIdx.z, tb = z & 31, ey = z >> 5;
  const ushort_t* src = SPKB + ((size_t)tb * ROWS + srcBase + ey * 96) * N;
  ushort_t* d = dst + (size_t)z * N * 96;
  int n0 = blockIdx.x * 32, c0 = blockIdx.y * 32;
  int t = threadIdx.x, nn = t & 31, cs = t >> 5;
#pragma unroll
  for (int l = 0; l < 4; ++l) {
    int cc = cs + 8 * l;
    tile[cc][nn] = src[(size_t)(c0 + cc) * N + n0 + nn];
  }
  __syncthreads();
  int cc2 = t & 31, ns = t >> 5;
#pragma unroll
  for (int l = 0; l < 4; ++l) {
    int nn2 = ns + 8 * l;
    d[(size_t)(n0 + nn2) * 96 + c0 + cc2] = tile[cc2][nn2];
  }
}

// ---------------- attn[bi][n][m] = sum_c QT[bi][n][c]*KT[tb][m][c]  (bf16 MFMA, exact) -------
__global__ __launch_bounds__(256) void attn_mfma(
    const ushort_t* __restrict__ QT, const ushort_t* __restrict__ KT, ushort_t* __restrict__ ATTNB)
{
  int bi = blockIdx.y, tb = bi & 31;
  const ushort_t* q  = QT + (size_t)bi * N * 96;
  const ushort_t* kk = KT + (size_t)tb * N * 96;
  ushort_t* ob = ATTNB + (size_t)bi * N * N;
  int m0 = blockIdx.x * 128;
  int t = threadIdx.x, w = t >> 6, l = t & 63;
  int lr = l & 15, lk = l >> 4;
  int nb = w * 64;
  f4v acc[4][8] = {};
  for (int kt = 0; kt < 96; kt += 32) {
    bf8v a[4], b[8];
#pragma unroll
    for (int rt = 0; rt < 4; ++rt)
      a[rt] = *reinterpret_cast<const bf8v*>(q + (size_t)(nb + rt * 16 + lr) * 96 + kt + lk * 8);
#pragma unroll
    for (int ct = 0; ct < 8; ++ct)
      b[ct] = *reinterpret_cast<const bf8v*>(kk + (size_t)(m0 + ct * 16 + lr) * 96 + kt + lk * 8);
#pragma unroll
    for (int rt = 0; rt < 4; ++rt)
#pragma unroll
      for (int ct = 0; ct < 8; ++ct)
        acc[rt][ct] = __builtin_amdgcn_mfma_f32_16x16x32_bf16(a[rt], b[ct], acc[rt][ct], 0, 0, 0);
  }
#pragma unroll
  for (int rt = 0; rt < 4; ++rt)
#pragma unroll
    for (int ct = 0; ct < 8; ++ct)
#pragma unroll
      for (int r = 0; r < 4; ++r) {
        int n = nb + rt * 16 + lk * 4 + r;
        int m = m0 + ct * 16 + lr;
        float v = acc[rt][ct][r];   // exact int <= 96
        ob[(size_t)n * N + m] = (ushort_t)(__builtin_bit_cast(unsigned, v) >> 16);
      }
}

// ---------------- res[bi][n][d] = sum_m ATTNB[bi][n][m]*v[tb][d][m]  (bf16 MFMA, exact) ------
__global__ __launch_bounds__(256) void res_mfma(
    const ushort_t* __restrict__ ATTNB, const ushort_t* __restrict__ SPKB, float* __restrict__ RES)
{
  int bi = blockIdx.y, tb = bi & 31;
  const ushort_t* A = ATTNB + (size_t)bi * N * N;
  const ushort_t* V = SPKB + ((size_t)tb * ROWS + 96) * N;  // v spikes (384 d, 256 m)
  float* ob = RES + (size_t)bi * N * C;
  int d0 = blockIdx.x * 96;
  int t = threadIdx.x, w = t >> 6, l = t & 63;
  int lr = l & 15, lk = l >> 4;
  int nb = w * 64;
  f4v acc[4][6] = {};
  for (int kt = 0; kt < 256; kt += 32) {
    bf8v a[4], b[6];
#pragma unroll
    for (int rt = 0; rt < 4; ++rt)
      a[rt] = *reinterpret_cast<const bf8v*>(A + (size_t)(nb + rt * 16 + lr) * N + kt + lk * 8);
#pragma unroll
    for (int ct = 0; ct < 6; ++ct)
      b[ct] = *reinterpret_cast<const bf8v*>(V + (size_t)(d0 + ct * 16 + lr) * N + kt + lk * 8);
#pragma unroll
    for (int rt = 0; rt < 4; ++rt)
#pragma unroll
      for (int ct = 0; ct < 6; ++ct)
        acc[rt][ct] = __builtin_amdgcn_mfma_f32_16x16x32_bf16(a[rt], b[ct], acc[rt][ct], 0, 0, 0);
  }
#pragma unroll
  for (int rt = 0; rt < 4; ++rt)
#pragma unroll
    for (int ct = 0; ct < 6; ++ct)
#pragma unroll
      for (int r = 0; r < 4; ++r) {
        int n = nb + rt * 16 + lk * 4 + r;
        int d = d0 + ct * 16 + lr;
        ob[(size_t)n * C + d] = acc[rt][ct][r];  // exact int <= 24576
      }
}

// ---------------- y[tb,d,n] = sum_e w[tb,e,n]*res_spk[e,tb,n,d] ----------------
__global__ __launch_bounds__(1024) void y_kernel(
    const float* __restrict__ SPK, const float* __restrict__ RES, float* __restrict__ Y)
{
  __shared__ float tile[32][33];
  int tb = blockIdx.z;
  int d0 = blockIdx.y * 32, n0 = blockIdx.x * 32;
  int tx = threadIdx.x, ty = threadIdx.y;
  int n = n0 + ty, d = d0 + tx;
  const float* wrow = SPK + (size_t)tb * ROWS * N + 480 * N;
  float v = 0.0f;
#pragma unroll
  for (int e = 0; e < 4; ++e) {
    float w = wrow[e * N + n];
    float r = RES[((size_t)(e * TB + tb) * N + n) * C + d];
    v += w * r;
  }
  tile[ty][tx] = v;
  __syncthreads();
  Y[(size_t)tb * C * N + (size_t)(d0 + ty) * N + n0 + tx] = tile[tx][ty];
}

// ---------------- LIF(pp) + residual: out = x + spike ----------------
__global__ __launch_bounds__(256) void lif_addx(
    const float* __restrict__ pp, const float* __restrict__ xin, float* __restrict__ out)
{
  int j = blockIdx.x * 256 + threadIdx.x;
  int b = blockIdx.y;
  float mem = 0.0f;
#pragma unroll
  for (int t = 0; t < 4; ++t) {
    size_t idx = (size_t)(t * 8 + b) * (C * N) + j;
    float x = pp[idx];
    mem += (x - mem) * 0.5f;
    float sp = (mem >= 1.0f) ? 1.0f : 0.0f;
    out[idx] = xin[idx] + sp;
    mem = (sp != 0.0f) ? 0.0f : mem;
  }
}

// ---------------- depthwise 3x3 + BN + LIF + gate ----------------
__global__ __launch_bounds__(256) void dwconv_kernel(
    const float* __restrict__ H, const float* __restrict__ DW,
    const float* __restrict__ aS, const float* __restrict__ aB, float* __restrict__ M)
{
  int u = blockIdx.x * 256 + threadIdx.x;
  int n = u & 255;
  int ch = (u >> 8) & 1023;
  int b = u >> 18;
  int px = n & 15, py = n >> 4;
  float w[9];
#pragma unroll
  for (int i = 0; i < 9; ++i) w[i] = DW[ch * 9 + i];
  float s = aS[ch], bb = aB[ch];
  float mem = 0.0f;
#pragma unroll
  for (int t = 0; t < 4; ++t) {
    const float* hp = H + ((size_t)(t * 8 + b) * HID + ch) * N;
    float acc = 0.0f;
#pragma unroll
    for (int dy = 0; dy < 3; ++dy) {
      int yy = py + dy - 1;
      if (yy < 0 || yy > 15) continue;
#pragma unroll
      for (int dx = 0; dx < 3; ++dx) {
        int xx = px + dx - 1;
        if (xx < 0 || xx > 15) continue;
        acc += hp[yy * 16 + xx] * w[dy * 3 + dx];
      }
    }
    float z = acc * s + bb;
    mem += (z - mem) * 0.5f;
    float sp = (mem >= 1.0f) ? 1.0f : 0.0f;
    mem = (sp != 0.0f) ? 0.0f : mem;
    float x2 = H[((size_t)(t * 8 + b) * HID + HH + ch) * N + n];
    M[((size_t)(t * 8 + b) * HH + ch) * N + n] = sp * x2;
  }
}

// ---------------- final: out += lif(f2) ----------------
__global__ __launch_bounds__(256) void lif_accum(const float* __restrict__ f2, float* __restrict__ out)
{
  int j = blockIdx.x * 256 + threadIdx.x;
  int b = blockIdx.y;
  float mem = 0.0f;
#pragma unroll
  for (int t = 0; t < 4; ++t) {
    size_t idx = (size_t)(t * 8 + b) * (C * N) + j;
    float x = f2[idx];
    mem += (x - mem) * 0.5f;
    float sp = (mem >= 1.0f) ? 1.0f : 0.0f;
    out[idx] += sp;
    mem = (sp != 0.0f) ? 0.0f : mem;
  }
}

} // namespace

extern "C" void kernel_launch(void* const* d_in, const int* in_sizes, int n_in,
                              void* d_out, int out_size, void* d_ws, size_t ws_size,
                              hipStream_t stream)
{
  const float* x         = (const float*)d_in[0];
  const float* k_w       = (const float*)d_in[2];
  const float* v_w       = (const float*)d_in[3];
  const float* router_w  = (const float*)d_in[4];
  const float* router_b  = (const float*)d_in[5];
  const float* router_g  = (const float*)d_in[6];
  const float* router_be = (const float*)d_in[7];
  const float* exp_w     = (const float*)d_in[8];
  const float* exp_g     = (const float*)d_in[9];
  const float* exp_b     = (const float*)d_in[10];
  const float* proj_w    = (const float*)d_in[11];
  const float* proj_b    = (const float*)d_in[12];
  const float* proj_g    = (const float*)d_in[13];
  const float* proj_be   = (const float*)d_in[14];
  const float* fc1_w     = (const float*)d_in[15];
  const float* fc1_b     = (const float*)d_in[16];
  const float* fc1_g     = (const float*)d_in[17];
  const float* fc1_be    = (const float*)d_in[18];
  const float* dw_w      = (const float*)d_in[19];
  const float* dw_b      = (const float*)d_in[20];
  const float* dw_g      = (const float*)d_in[21];
  const float* dw_be     = (const float*)d_in[22];
  const float* fc2_w     = (const float*)d_in[23];
  const float* fc2_b     = (const float*)d_in[24];
  const float* fc2_g     = (const float*)d_in[25];
  const float* fc2_be    = (const float*)d_in[26];

  float* ws  = (float*)d_ws;
  float* out = (float*)d_out;
  ushort_t* spkb = (ushort_t*)(ws + O_SPKB);
  ushort_t* qt   = (ushort_t*)(ws + O_QT);
  ushort_t* ktb  = (ushort_t*)(ws + O_KT);
  ushort_t* attb = (ushort_t*)(ws + O_ATTNB);
  dim3 blk(256);

  // weight pack + folded BN affines
  pack_kernel<<<1302, blk, 0, stream>>>(k_w, v_w, router_w, router_b, router_g, router_be,
                                        exp_w, exp_g, exp_b,
                                        ws + O_WPACK, ws + O_A1S, ws + O_A1B);
  aff_kernel<<<2, blk, 0, stream>>>(proj_g, proj_b, proj_be, ws + O_APS, ws + O_APB, 384);
  aff_kernel<<<8, blk, 0, stream>>>(fc1_g, fc1_b, fc1_be, ws + O_AHS, ws + O_AHB, 2048);
  aff_kernel<<<4, blk, 0, stream>>>(dw_g, dw_b, dw_be, ws + O_ADS, ws + O_ADB, 1024);
  aff_kernel<<<2, blk, 0, stream>>>(fc2_g, fc2_b, fc2_be, ws + O_AFS, ws + O_AFB, 384);

  // fused k/v/router/q projection GEMM (868 rows) + BN affine epilogue
  gemm2<<<dim3(2, 7, 32), blk, 0, stream>>>(ws + O_WPACK, x, ws + O_PRE,
                                            ws + O_A1S, ws + O_A1B,
                                            ROWS, C, (long)C * N, (long)ROWS * N);
  // LIF -> fp32 spikes in place + bf16 spike copy
  lif_pre<<<dim3(ROWS, 8), blk, 0, stream>>>(ws + O_PRE, spkb);
  // K-major transposes for MFMA operands
  transpose_spk<<<dim3(8, 3, 32),  blk, 0, stream>>>(spkb, ktb, 0);
  transpose_spk<<<dim3(8, 3, 128), blk, 0, stream>>>(spkb, qt, 484);
  // attn = q^T k (exact, bf16 MFMA, output bf16 ints <= 96)
  attn_mfma<<<dim3(2, 128), blk, 0, stream>>>(qt, ktb, attb);
  // res = attn @ v^T (exact ints <= 24576, fp32 out)
  res_mfma<<<dim3(4, 128), blk, 0, stream>>>(attb, spkb, ws + O_RES);
  // LIF on res
  lif_kernel<<<dim3(N * C / 256, 32), blk, 0, stream>>>(ws + O_RES, N * C);
  // router-weighted expert sum -> y (TB,C,N)
  y_kernel<<<dim3(8, 12, 32), dim3(32, 32), 0, stream>>>(ws + O_PRE, ws + O_RES, ws + O_Y);
  // proj GEMM + BN
  gemm2<<<dim3(2, 3, 32), blk, 0, stream>>>(proj_w, ws + O_Y, ws + O_PP,
                                            ws + O_APS, ws + O_APB,
                                            C, C, (long)C * N, (long)C * N);
  // x = x + lif(proj)
  lif_addx<<<dim3(384, 8), blk, 0, stream>>>(ws + O_PP, x, out);

  // fc1 GEMM + BN
  gemm2<<<dim3(2, 16, 32), blk, 0, stream>>>(fc1_w, out, ws + O_H,
                                             ws + O_AHS, ws + O_AHB,
                                             HID, C, (long)C * N, (long)HID * N);
  lif_kernel<<<dim3(HID * N / 256, 8), blk, 0, stream>>>(ws + O_H, HID * N);
  // depthwise conv + BN + LIF + gate
  dwconv_kernel<<<dim3(8 * HH * N / 256), blk, 0, stream>>>(ws + O_H, dw_w,
                                                            ws + O_ADS, ws + O_ADB, ws + O_M);
  // fc2 GEMM + BN
  gemm2<<<dim3(2, 3, 32), blk, 0, stream>>>(fc2_w, ws + O_M, ws + O_F2,
                                            ws + O_AFS, ws + O_AFB,
                                            C, HH, (long)HH * N, (long)C * N);
  // out += lif(fc2)
  lif_accum<<<dim3(384, 8), blk, 0, stream>>>(ws + O_F2, out);
}

// Round 3
// 722.716 us; speedup vs baseline: 1.2955x; 1.2955x over previous
//
#include <hip/hip_runtime.h>
#include <cstdint>
#include <cstddef>

namespace {

typedef unsigned short ushort_t;
typedef __attribute__((ext_vector_type(8))) short bf8v;   // 8 bf16 in 4 VGPR
typedef __attribute__((ext_vector_type(4))) float f4v;    // MFMA accumulator

constexpr float BNS = 0.99999500003749973f; // 1/sqrt(1+1e-5)

constexpr int TB = 32;      // T*B
constexpr int C  = 384;
constexpr int N  = 256;     // H*W
constexpr int ROWS = 868;   // 96 k + 384 v + 4 router + 384 q(E*ed)
constexpr int HID = 2048;
constexpr int HH  = 1024;

// workspace offsets (in floats)
constexpr size_t O_WPACK = 0;                       // 868*384 = 333312
constexpr size_t O_A1S = 333312;
constexpr size_t O_A1B = O_A1S + 868;
constexpr size_t O_APS = O_A1B + 868;
constexpr size_t O_APB = O_APS + 384;
constexpr size_t O_AHS = O_APB + 384;
constexpr size_t O_AHB = O_AHS + 2048;
constexpr size_t O_ADS = O_AHB + 2048;
constexpr size_t O_ADB = O_ADS + 1024;
constexpr size_t O_AFS = O_ADB + 1024;
constexpr size_t O_AFB = O_AFS + 384;               // ends 342728
constexpr size_t O_PRE  = 342784;                   // TB*ROWS*N fp32 = 7,110,656
constexpr size_t O_SPKB = 7453440;                  // bf16 spikes [tb][868][256] -> 3,555,328 floats
constexpr size_t O_QT   = 11008768;                 // bf16 [e*32+tb][256][96]    -> 1,572,864 floats
constexpr size_t O_KT   = 12581632;                 // bf16 [tb][256][96]         ->   393,216 floats
constexpr size_t O_ATTNB= 12974848;                 // bf16 [bi][256][256]        -> 4,194,304 floats
constexpr size_t O_RES  = 17169152;                 // fp32 [bi][256][384]        -> 12,582,912
constexpr size_t O_Y    = 11008768;                 // fp32 (over QT/KT, dead)     3,145,728
constexpr size_t O_PP   = 14154496;                 // fp32 (over ATTNB, dead)     3,145,728
constexpr size_t O_H    = 7453440;                  // fp32 16,777,216 (phase B)
constexpr size_t O_M    = 24230656;                 // fp32  8,388,608
constexpr size_t O_F2   = O_PRE;                    // fp32  3,145,728 (PRE dead)

// ---------------- pack weights + affines ----------------
__global__ __launch_bounds__(256) void pack_kernel(
    const float* __restrict__ kw, const float* __restrict__ vw,
    const float* __restrict__ rw, const float* __restrict__ rb,
    const float* __restrict__ rg, const float* __restrict__ rbe,
    const float* __restrict__ ew, const float* __restrict__ eg,
    const float* __restrict__ eb,
    float* __restrict__ WP, float* __restrict__ a1s, float* __restrict__ a1b)
{
  int u = blockIdx.x * 256 + threadIdx.x;
  if (u < ROWS * C) {
    int r = u / C, d = u % C;
    float w;
    if (r < 96)       w = kw[r * C + d];
    else if (r < 480) w = vw[(r - 96) * C + d];
    else if (r < 484) w = rw[(r - 480) * C + d];
    else              w = ew[(r - 484) * C + d];
    WP[u] = w;
  }
  if (u < ROWS) {
    float s, b;
    if (u < 480)      { s = 1.0f; b = 0.0f; }
    else if (u < 484) { int e = u - 480; s = rg[e] * BNS; b = rb[e] * rg[e] * BNS + rbe[e]; }
    else              { int j = u - 484; s = eg[j] * BNS; b = eb[j]; }
    a1s[u] = s; a1b[u] = b;
  }
}

__global__ __launch_bounds__(256) void aff_kernel(
    const float* __restrict__ g, const float* __restrict__ bias,
    const float* __restrict__ be, float* __restrict__ s, float* __restrict__ b, int n)
{
  int u = blockIdx.x * 256 + threadIdx.x;
  if (u < n) { s[u] = g[u] * BNS; b[u] = bias[u] * g[u] * BNS + be[u]; }
}

// ------- fp32 GEMM, tile TO x 64, 256 thr, RPT x 4 acc: OUT[b,o,n]=(sum W[o,d]X[b,d,n])*s+b ----
// Accumulation: k ascending, BK=16 — identical order to the passing R1/R2 kernels.
template<int TO>
__global__ __launch_bounds__(256) void gemm3(
    const float* __restrict__ W, const float* __restrict__ X, float* __restrict__ OUT,
    const float* __restrict__ aS, const float* __restrict__ aB,
    int O, int D, long xStride, long oStride)
{
  constexpr int RPT = TO / 16;               // 8 or 4 output rows per thread
  __shared__ float Wt[16][TO + 4];           // row stride 132/68 floats -> 16B-aligned rows
  __shared__ float Xt[16][68];
  const float* Xb = X + (size_t)blockIdx.z * xStride;
  float* Ob = OUT + (size_t)blockIdx.z * oStride;
  int n0 = blockIdx.x * 64, o0 = blockIdx.y * TO;
  int t = threadIdx.x, tx = t & 15, ty = t >> 4;
  float acc[RPT][4] = {};
  for (int kt = 0; kt < D; kt += 16) {
    // stage W tile (transposed into [k][o])
#pragma unroll
    for (int l = 0; l < RPT; ++l) {
      int rr = ty + 16 * l, orow = o0 + rr;
      Wt[tx][rr] = (orow < O) ? W[(size_t)orow * D + kt + tx] : 0.0f;
    }
    // stage X tile [k][n]
    {
      int r2 = t >> 6, c2 = t & 63;
#pragma unroll
      for (int l = 0; l < 4; ++l)
        Xt[r2 + 4 * l][c2] = Xb[(size_t)(kt + r2 + 4 * l) * N + n0 + c2];
    }
    __syncthreads();
#pragma unroll
    for (int k = 0; k < 16; ++k) {
      float4 bv = *reinterpret_cast<const float4*>(&Xt[k][tx * 4]);
      float b[4] = {bv.x, bv.y, bv.z, bv.w};
#pragma unroll
      for (int g = 0; g < RPT / 4; ++g) {
        float4 av = *reinterpret_cast<const float4*>(&Wt[k][ty * RPT + g * 4]);
        float a[4] = {av.x, av.y, av.z, av.w};
#pragma unroll
        for (int i = 0; i < 4; ++i)
#pragma unroll
          for (int j = 0; j < 4; ++j)
            acc[g * 4 + i][j] += a[i] * b[j];
      }
    }
    __syncthreads();
  }
#pragma unroll
  for (int i = 0; i < RPT; ++i) {
    int orow = o0 + ty * RPT + i;
    if (orow < O) {
      float s = aS[orow], bb = aB[orow];
#pragma unroll
      for (int j = 0; j < 4; ++j)
        Ob[(size_t)orow * N + n0 + tx * 4 + j] = acc[i][j] * s + bb;
    }
  }
}

// ---------------- LIF on PRE (in place) + bf16 spike copy ----------------
__global__ __launch_bounds__(256) void lif_pre(float* __restrict__ p, ushort_t* __restrict__ spkb)
{
  int j = blockIdx.x * 256 + threadIdx.x;
  int b = blockIdx.y;
  float mem = 0.0f;
#pragma unroll
  for (int t = 0; t < 4; ++t) {
    size_t idx = (size_t)(t * 8 + b) * ((size_t)ROWS * N) + j;
    float x = p[idx];
    mem += (x - mem) * 0.5f;
    bool fire = (mem >= 1.0f);
    p[idx] = fire ? 1.0f : 0.0f;
    spkb[idx] = fire ? (ushort_t)0x3F80 : (ushort_t)0;
    mem = fire ? 0.0f : mem;
  }
}

// ---------------- generic LIF (in place): p shape (nOuter, TB, FN) ----------------
__global__ __launch_bounds__(256) void lif_kernel(float* __restrict__ p, int FN)
{
  int j = blockIdx.x * 256 + threadIdx.x;
  int yb = blockIdx.y; int b = yb & 7; int e = yb >> 3;
  float mem = 0.0f;
#pragma unroll
  for (int t = 0; t < 4; ++t) {
    size_t idx = (size_t)(e * 32 + t * 8 + b) * FN + j;
    float x = p[idx];
    mem += (x - mem) * 0.5f;
    float sp = (mem >= 1.0f) ? 1.0f : 0.0f;
    p[idx] = sp;
    mem = (sp != 0.0f) ? 0.0f : mem;
  }
}

// ---------------- transpose spikes: SPKB[tb][base+ey*96+c][n] -> dst[ey*32+tb][n][c] ----------
__global__ __launch_bounds__(256) void transpose_spk(
    const ushort_t* __restrict__ SPKB, ushort_t* __restrict__ dst, int srcBase)
{
  __shared__ ushort_t tile[32][33];
  int z = blockIdx.z, tb = z & 31, ey = z >> 5;
  const ushort_t* src = SPKB + ((size_t)tb * ROWS + srcBase + ey * 96) * N;
  ushort_t* d = dst + (size_t)z * N * 96;
  int n0 = blockIdx.x * 32, c0 = blockIdx.y * 32;
  int t = threadIdx.x, nn = t & 31, cs = t >> 5;
#pragma unroll
  for (int l = 0; l < 4; ++l) {
    int cc = cs + 8 * l;
    tile[cc][nn] = src[(size_t)(c0 + cc) * N + n0 + nn];
  }
  __syncthreads();
  int cc2 = t & 31, ns = t >> 5;
#pragma unroll
  for (int l = 0; l < 4; ++l) {
    int nn2 = ns + 8 * l;
    d[(size_t)(n0 + nn2) * 96 + c0 + cc2] = tile[cc2][nn2];
  }
}

// ---------------- attn[bi][n][m] = sum_c QT[bi][n][c]*KT[tb][m][c]  (bf16 MFMA, exact) -------
__global__ __launch_bounds__(256) void attn_mfma(
    const ushort_t* __restrict__ QT, const ushort_t* __restrict__ KT, ushort_t* __restrict__ ATTNB)
{
  int bi = blockIdx.y, tb = bi & 31;
  const ushort_t* q  = QT + (size_t)bi * N * 96;
  const ushort_t* kk = KT + (size_t)tb * N * 96;
  ushort_t* ob = ATTNB + (size_t)bi * N * N;
  int m0 = blockIdx.x * 128;
  int t = threadIdx.x, w = t >> 6, l = t & 63;
  int lr = l & 15, lk = l >> 4;
  int nb = w * 64;
  f4v acc[4][8] = {};
  for (int kt = 0; kt < 96; kt += 32) {
    bf8v a[4], b[8];
#pragma unroll
    for (int rt = 0; rt < 4; ++rt)
      a[rt] = *reinterpret_cast<const bf8v*>(q + (size_t)(nb + rt * 16 + lr) * 96 + kt + lk * 8);
#pragma unroll
    for (int ct = 0; ct < 8; ++ct)
      b[ct] = *reinterpret_cast<const bf8v*>(kk + (size_t)(m0 + ct * 16 + lr) * 96 + kt + lk * 8);
#pragma unroll
    for (int rt = 0; rt < 4; ++rt)
#pragma unroll
      for (int ct = 0; ct < 8; ++ct)
        acc[rt][ct] = __builtin_amdgcn_mfma_f32_16x16x32_bf16(a[rt], b[ct], acc[rt][ct], 0, 0, 0);
  }
#pragma unroll
  for (int rt = 0; rt < 4; ++rt)
#pragma unroll
    for (int ct = 0; ct < 8; ++ct)
#pragma unroll
      for (int r = 0; r < 4; ++r) {
        int n = nb + rt * 16 + lk * 4 + r;
        int m = m0 + ct * 16 + lr;
        float v = acc[rt][ct][r];   // exact int <= 96
        ob[(size_t)n * N + m] = (ushort_t)(__builtin_bit_cast(unsigned, v) >> 16);
      }
}

// ---------------- res[bi][n][d] = sum_m ATTNB[bi][n][m]*v[tb][d][m]  (bf16 MFMA, exact) ------
__global__ __launch_bounds__(256) void res_mfma(
    const ushort_t* __restrict__ ATTNB, const ushort_t* __restrict__ SPKB, float* __restrict__ RES)
{
  int bi = blockIdx.y, tb = bi & 31;
  const ushort_t* A = ATTNB + (size_t)bi * N * N;
  const ushort_t* V = SPKB + ((size_t)tb * ROWS + 96) * N;  // v spikes (384 d, 256 m)
  float* ob = RES + (size_t)bi * N * C;
  int d0 = blockIdx.x * 96;
  int t = threadIdx.x, w = t >> 6, l = t & 63;
  int lr = l & 15, lk = l >> 4;
  int nb = w * 64;
  f4v acc[4][6] = {};
  for (int kt = 0; kt < 256; kt += 32) {
    bf8v a[4], b[6];
#pragma unroll
    for (int rt = 0; rt < 4; ++rt)
      a[rt] = *reinterpret_cast<const bf8v*>(A + (size_t)(nb + rt * 16 + lr) * N + kt + lk * 8);
#pragma unroll
    for (int ct = 0; ct < 6; ++ct)
      b[ct] = *reinterpret_cast<const bf8v*>(V + (size_t)(d0 + ct * 16 + lr) * N + kt + lk * 8);
#pragma unroll
    for (int rt = 0; rt < 4; ++rt)
#pragma unroll
      for (int ct = 0; ct < 6; ++ct)
        acc[rt][ct] = __builtin_amdgcn_mfma_f32_16x16x32_bf16(a[rt], b[ct], acc[rt][ct], 0, 0, 0);
  }
#pragma unroll
  for (int rt = 0; rt < 4; ++rt)
#pragma unroll
    for (int ct = 0; ct < 6; ++ct)
#pragma unroll
      for (int r = 0; r < 4; ++r) {
        int n = nb + rt * 16 + lk * 4 + r;
        int d = d0 + ct * 16 + lr;
        ob[(size_t)n * C + d] = acc[rt][ct][r];  // exact int <= 24576
      }
}

// ---------------- y[tb,d,n] = sum_e w[tb,e,n]*res_spk[e,tb,n,d] ----------------
__global__ __launch_bounds__(1024) void y_kernel(
    const float* __restrict__ SPK, const float* __restrict__ RES, float* __restrict__ Y)
{
  __shared__ float tile[32][33];
  int tb = blockIdx.z;
  int d0 = blockIdx.y * 32, n0 = blockIdx.x * 32;
  int tx = threadIdx.x, ty = threadIdx.y;
  int n = n0 + ty, d = d0 + tx;
  const float* wrow = SPK + (size_t)tb * ROWS * N + 480 * N;
  float v = 0.0f;
#pragma unroll
  for (int e = 0; e < 4; ++e) {
    float w = wrow[e * N + n];
    float r = RES[((size_t)(e * TB + tb) * N + n) * C + d];
    v += w * r;
  }
  tile[ty][tx] = v;
  __syncthreads();
  Y[(size_t)tb * C * N + (size_t)(d0 + ty) * N + n0 + tx] = tile[tx][ty];
}

// ---------------- LIF(pp) + residual: out = x + spike ----------------
__global__ __launch_bounds__(256) void lif_addx(
    const float* __restrict__ pp, const float* __restrict__ xin, float* __restrict__ out)
{
  int j = blockIdx.x * 256 + threadIdx.x;
  int b = blockIdx.y;
  float mem = 0.0f;
#pragma unroll
  for (int t = 0; t < 4; ++t) {
    size_t idx = (size_t)(t * 8 + b) * (C * N) + j;
    float x = pp[idx];
    mem += (x - mem) * 0.5f;
    float sp = (mem >= 1.0f) ? 1.0f : 0.0f;
    out[idx] = xin[idx] + sp;
    mem = (sp != 0.0f) ? 0.0f : mem;
  }
}

// ---------------- depthwise 3x3 + BN + LIF + gate ----------------
__global__ __launch_bounds__(256) void dwconv_kernel(
    const float* __restrict__ H, const float* __restrict__ DW,
    const float* __restrict__ aS, const float* __restrict__ aB, float* __restrict__ M)
{
  int u = blockIdx.x * 256 + threadIdx.x;
  int n = u & 255;
  int ch = (u >> 8) & 1023;
  int b = u >> 18;
  int px = n & 15, py = n >> 4;
  float w[9];
#pragma unroll
  for (int i = 0; i < 9; ++i) w[i] = DW[ch * 9 + i];
  float s = aS[ch], bb = aB[ch];
  float mem = 0.0f;
#pragma unroll
  for (int t = 0; t < 4; ++t) {
    const float* hp = H + ((size_t)(t * 8 + b) * HID + ch) * N;
    float acc = 0.0f;
#pragma unroll
    for (int dy = 0; dy < 3; ++dy) {
      int yy = py + dy - 1;
      if (yy < 0 || yy > 15) continue;
#pragma unroll
      for (int dx = 0; dx < 3; ++dx) {
        int xx = px + dx - 1;
        if (xx < 0 || xx > 15) continue;
        acc += hp[yy * 16 + xx] * w[dy * 3 + dx];
      }
    }
    float z = acc * s + bb;
    mem += (z - mem) * 0.5f;
    float sp = (mem >= 1.0f) ? 1.0f : 0.0f;
    mem = (sp != 0.0f) ? 0.0f : mem;
    float x2 = H[((size_t)(t * 8 + b) * HID + HH + ch) * N + n];
    M[((size_t)(t * 8 + b) * HH + ch) * N + n] = sp * x2;
  }
}

// ---------------- final: out += lif(f2) ----------------
__global__ __launch_bounds__(256) void lif_accum(const float* __restrict__ f2, float* __restrict__ out)
{
  int j = blockIdx.x * 256 + threadIdx.x;
  int b = blockIdx.y;
  float mem = 0.0f;
#pragma unroll
  for (int t = 0; t < 4; ++t) {
    size_t idx = (size_t)(t * 8 + b) * (C * N) + j;
    float x = f2[idx];
    mem += (x - mem) * 0.5f;
    float sp = (mem >= 1.0f) ? 1.0f : 0.0f;
    out[idx] += sp;
    mem = (sp != 0.0f) ? 0.0f : mem;
  }
}

} // namespace

extern "C" void kernel_launch(void* const* d_in, const int* in_sizes, int n_in,
                              void* d_out, int out_size, void* d_ws, size_t ws_size,
                              hipStream_t stream)
{
  const float* x         = (const float*)d_in[0];
  const float* k_w       = (const float*)d_in[2];
  const float* v_w       = (const float*)d_in[3];
  const float* router_w  = (const float*)d_in[4];
  const float* router_b  = (const float*)d_in[5];
  const float* router_g  = (const float*)d_in[6];
  const float* router_be = (const float*)d_in[7];
  const float* exp_w     = (const float*)d_in[8];
  const float* exp_g     = (const float*)d_in[9];
  const float* exp_b     = (const float*)d_in[10];
  const float* proj_w    = (const float*)d_in[11];
  const float* proj_b    = (const float*)d_in[12];
  const float* proj_g    = (const float*)d_in[13];
  const float* proj_be   = (const float*)d_in[14];
  const float* fc1_w     = (const float*)d_in[15];
  const float* fc1_b     = (const float*)d_in[16];
  const float* fc1_g     = (const float*)d_in[17];
  const float* fc1_be    = (const float*)d_in[18];
  const float* dw_w      = (const float*)d_in[19];
  const float* dw_b      = (const float*)d_in[20];
  const float* dw_g      = (const float*)d_in[21];
  const float* dw_be     = (const float*)d_in[22];
  const float* fc2_w     = (const float*)d_in[23];
  const float* fc2_b     = (const float*)d_in[24];
  const float* fc2_g     = (const float*)d_in[25];
  const float* fc2_be    = (const float*)d_in[26];

  float* ws  = (float*)d_ws;
  float* out = (float*)d_out;
  ushort_t* spkb = (ushort_t*)(ws + O_SPKB);
  ushort_t* qt   = (ushort_t*)(ws + O_QT);
  ushort_t* ktb  = (ushort_t*)(ws + O_KT);
  ushort_t* attb = (ushort_t*)(ws + O_ATTNB);
  dim3 blk(256);

  // weight pack + folded BN affines
  pack_kernel<<<1302, blk, 0, stream>>>(k_w, v_w, router_w, router_b, router_g, router_be,
                                        exp_w, exp_g, exp_b,
                                        ws + O_WPACK, ws + O_A1S, ws + O_A1B);
  aff_kernel<<<2, blk, 0, stream>>>(proj_g, proj_b, proj_be, ws + O_APS, ws + O_APB, 384);
  aff_kernel<<<8, blk, 0, stream>>>(fc1_g, fc1_b, fc1_be, ws + O_AHS, ws + O_AHB, 2048);
  aff_kernel<<<4, blk, 0, stream>>>(dw_g, dw_b, dw_be, ws + O_ADS, ws + O_ADB, 1024);
  aff_kernel<<<2, blk, 0, stream>>>(fc2_g, fc2_b, fc2_be, ws + O_AFS, ws + O_AFB, 384);

  // fused k/v/router/q projection GEMM (868 rows) + BN affine epilogue
  gemm3<128><<<dim3(4, 7, 32), blk, 0, stream>>>(ws + O_WPACK, x, ws + O_PRE,
                                                 ws + O_A1S, ws + O_A1B,
                                                 ROWS, C, (long)C * N, (long)ROWS * N);
  // LIF -> fp32 spikes in place + bf16 spike copy
  lif_pre<<<dim3(ROWS, 8), blk, 0, stream>>>(ws + O_PRE, spkb);
  // K-major transposes for MFMA operands
  transpose_spk<<<dim3(8, 3, 32),  blk, 0, stream>>>(spkb, ktb, 0);
  transpose_spk<<<dim3(8, 3, 128), blk, 0, stream>>>(spkb, qt, 484);
  // attn = q^T k (exact, bf16 MFMA, output bf16 ints <= 96)
  attn_mfma<<<dim3(2, 128), blk, 0, stream>>>(qt, ktb, attb);
  // res = attn @ v^T (exact ints <= 24576, fp32 out)
  res_mfma<<<dim3(4, 128), blk, 0, stream>>>(attb, spkb, ws + O_RES);
  // LIF on res
  lif_kernel<<<dim3(N * C / 256, 32), blk, 0, stream>>>(ws + O_RES, N * C);
  // router-weighted expert sum -> y (TB,C,N)
  y_kernel<<<dim3(8, 12, 32), dim3(32, 32), 0, stream>>>(ws + O_PRE, ws + O_RES, ws + O_Y);
  // proj GEMM + BN
  gemm3<64><<<dim3(4, 6, 32), blk, 0, stream>>>(proj_w, ws + O_Y, ws + O_PP,
                                                ws + O_APS, ws + O_APB,
                                                C, C, (long)C * N, (long)C * N);
  // x = x + lif(proj)
  lif_addx<<<dim3(384, 8), blk, 0, stream>>>(ws + O_PP, x, out);

  // fc1 GEMM + BN
  gemm3<128><<<dim3(4, 16, 32), blk, 0, stream>>>(fc1_w, out, ws + O_H,
                                                  ws + O_AHS, ws + O_AHB,
                                                  HID, C, (long)C * N, (long)HID * N);
  lif_kernel<<<dim3(HID * N / 256, 8), blk, 0, stream>>>(ws + O_H, HID * N);
  // depthwise conv + BN + LIF + gate
  dwconv_kernel<<<dim3(8 * HH * N / 256), blk, 0, stream>>>(ws + O_H, dw_w,
                                                            ws + O_ADS, ws + O_ADB, ws + O_M);
  // fc2 GEMM + BN
  gemm3<64><<<dim3(4, 6, 32), blk, 0, stream>>>(fc2_w, ws + O_M, ws + O_F2,
                                                ws + O_AFS, ws + O_AFB,
                                                C, HH, (long)HH * N, (long)C * N);
  // out += lif(fc2)
  lif_accum<<<dim3(384, 8), blk, 0, stream>>>(ws + O_F2, out);
}

// Round 4
// 590.639 us; speedup vs baseline: 1.5852x; 1.2236x over previous
//
#include <hip/hip_runtime.h>
#include <cstdint>
#include <cstddef>

namespace {

typedef unsigned short ushort_t;
typedef _Float16 half_t;
typedef __attribute__((ext_vector_type(8))) short bf8v;     // 8 bf16
typedef __attribute__((ext_vector_type(8))) _Float16 h8v;   // 8 fp16
typedef __attribute__((ext_vector_type(4))) float f4v;      // MFMA acc

constexpr float BNS = 0.99999500003749973f; // 1/sqrt(1+1e-5)

constexpr int TB = 32;
constexpr int C  = 384;
constexpr int N  = 256;
constexpr int ROWS = 868;   // 96 k + 384 v + 4 router + 384 q
constexpr int HID = 2048;
constexpr int HH  = 1024;

// ---- workspace layout (float units) ----
constexpr size_t O_A1S = 0,      O_A1B = 868;
constexpr size_t O_APS = 1736,   O_APB = 2120;
constexpr size_t O_AHS = 2504,   O_AHB = 4552;
constexpr size_t O_ADS = 6600,   O_ADB = 7624;
constexpr size_t O_AFS = 8648,   O_AFB = 9032;
constexpr size_t O_WPRE0 = 16384,   O_WPRE1 = 188416;    // 896x384 half each
constexpr size_t O_WPROJ0 = 360448, O_WPROJ1 = 434176;   // 384x384
constexpr size_t O_WFC10 = 507904,  O_WFC11 = 901120;    // 2048x384
constexpr size_t O_WFC20 = 1294336, O_WFC21 = 1490944;   // 384x1024
constexpr size_t O_PRE   = 1687552;                      // fp32 [32][868][256]
constexpr size_t O_WPACK = O_PRE;                        // fp32 868x384 (dead before PRE written)
constexpr size_t O_SPKB  = 8798208;                      // bf16 [32][868][256]
constexpr size_t O_QT    = 12353536;                     // bf16 [128][256][96]
constexpr size_t O_KT    = 13926400;                     // bf16 [32][256][96]
constexpr size_t O_ATTNB = 14319616;                     // bf16 [128][256][256]
constexpr size_t O_RES   = 18513920;                     // fp32 [128][256][384]
constexpr size_t O_XTPRE = 18513920;                     // half x2 [32][256][384] (dead before RES)
constexpr size_t O_Y     = 8798208;                      // fp32 (over SPKB, dead)
constexpr size_t O_XTPROJ= 12353536;                     // half x2 (over QT/KT/ATTNB-head, dead)
constexpr size_t O_PP    = 18513920;                     // fp32 (over RES, dead)
constexpr size_t O_XTFC1 = 1687552;                      // half x2 (over PRE, dead after y)
constexpr size_t O_H     = 4833280;                      // fp32 [32][2048][256] -> 21,610,496
constexpr size_t O_XTFC2 = 4833280;                      // half x2 [32][256][1024] (over H, dead)
constexpr size_t O_F2    = 13221888;                     // fp32 [32][384][256]
constexpr size_t O_M     = 21610496;                     // fp32 [32][1024][256] -> 29,999,104

// ---------------- pack weights + affines ----------------
__global__ __launch_bounds__(256) void pack_kernel(
    const float* __restrict__ kw, const float* __restrict__ vw,
    const float* __restrict__ rw, const float* __restrict__ rb,
    const float* __restrict__ rg, const float* __restrict__ rbe,
    const float* __restrict__ ew, const float* __restrict__ eg,
    const float* __restrict__ eb,
    float* __restrict__ WP, float* __restrict__ a1s, float* __restrict__ a1b)
{
  int u = blockIdx.x * 256 + threadIdx.x;
  if (u < ROWS * C) {
    int r = u / C, d = u % C;
    float w;
    if (r < 96)       w = kw[r * C + d];
    else if (r < 480) w = vw[(r - 96) * C + d];
    else if (r < 484) w = rw[(r - 480) * C + d];
    else              w = ew[(r - 484) * C + d];
    WP[u] = w;
  }
  if (u < ROWS) {
    float s, b;
    if (u < 480)      { s = 1.0f; b = 0.0f; }
    else if (u < 484) { int e = u - 480; s = rg[e] * BNS; b = rb[e] * rg[e] * BNS + rbe[e]; }
    else              { int j = u - 484; s = eg[j] * BNS; b = eb[j]; }
    a1s[u] = s; a1b[u] = b;
  }
}

__global__ __launch_bounds__(256) void aff_kernel(
    const float* __restrict__ g, const float* __restrict__ bias,
    const float* __restrict__ be, float* __restrict__ s, float* __restrict__ b, int n)
{
  int u = blockIdx.x * 256 + threadIdx.x;
  if (u < n) { s[u] = g[u] * BNS; b[u] = bias[u] * g[u] * BNS + be[u]; }
}

// ---------------- fp32 -> 2x fp16 weight split (K-major already), zero-padded rows ----------
__global__ __launch_bounds__(256) void split_w(
    const float* __restrict__ W, half_t* __restrict__ W0, half_t* __restrict__ W1,
    int O, int Opad, int D)
{
  int u = blockIdx.x * 256 + threadIdx.x;
  if (u >= Opad * D) return;
  int r = u / D;
  float v = (r < O) ? W[u] : 0.0f;
  half_t h0 = (half_t)v;
  half_t h1 = (half_t)(v - (float)h0);
  W0[u] = h0; W1[u] = h1;
}

// ---------------- X [tb][D][N] fp32 -> XT0,XT1 [tb][N][D] fp16 (transpose + split) ----------
__global__ __launch_bounds__(256) void split_xt(
    const float* __restrict__ X, half_t* __restrict__ X0, half_t* __restrict__ X1, int D)
{
  __shared__ float tile[32][33];
  int tb = blockIdx.z, n0 = blockIdx.x * 32, d0 = blockIdx.y * 32;
  const float* src = X + (size_t)tb * D * N;
  int t = threadIdx.x;
  int nn = t & 31, ds = t >> 5;
#pragma unroll
  for (int l = 0; l < 4; ++l) {
    int dd = ds + 8 * l;
    tile[dd][nn] = src[(size_t)(d0 + dd) * N + n0 + nn];
  }
  __syncthreads();
  int dd2 = t & 31, ns = t >> 5;
#pragma unroll
  for (int l = 0; l < 4; ++l) {
    int nn2 = ns + 8 * l;
    float v = tile[dd2][nn2];
    half_t h0 = (half_t)v;
    half_t h1 = (half_t)(v - (float)h0);
    size_t o = ((size_t)tb * N + n0 + nn2) * D + d0 + dd2;
    X0[o] = h0; X1[o] = h1;
  }
}

// ------- split-fp16 MFMA GEMM: OUT[tb][o][n] = (sum_d W[o][d]X[tb][d][n])*s[o]+b[o] ---------
// a = XT rows (n, K-major d), b = W rows (o, K-major d). 4 waves: wn=w&1, wo=w>>1.
// Per tile: 3 products w0x0 + w0x1 + w1x0 (w1x1 ~ 2^-24, dropped). Error ~2e-7 per row sum.
template<int RT, int CT>
__global__ __launch_bounds__(256) void sgemm(
    const half_t* __restrict__ X0, const half_t* __restrict__ X1,
    const half_t* __restrict__ W0, const half_t* __restrict__ W1,
    float* __restrict__ OUT, const float* __restrict__ aS, const float* __restrict__ aB,
    int O, int D)
{
  int tb = blockIdx.z;
  int n0 = blockIdx.x * (RT * 32);
  int o0 = blockIdx.y * (CT * 32);
  const half_t* Xb0 = X0 + (size_t)tb * N * D;
  const half_t* Xb1 = X1 + (size_t)tb * N * D;
  float* Ob = OUT + (size_t)tb * O * N;
  int t = threadIdx.x, w = t >> 6, l = t & 63;
  int lr = l & 15, lk = l >> 4;
  int nbase = n0 + (w & 1) * RT * 16;
  int obase = o0 + (w >> 1) * CT * 16;
  f4v acc[RT][CT] = {};
  for (int kt = 0; kt < D; kt += 32) {
    h8v a0[RT], a1[RT], b0[CT], b1[CT];
#pragma unroll
    for (int rt = 0; rt < RT; ++rt) {
      size_t ro = (size_t)(nbase + rt * 16 + lr) * D + kt + lk * 8;
      a0[rt] = *reinterpret_cast<const h8v*>(Xb0 + ro);
      a1[rt] = *reinterpret_cast<const h8v*>(Xb1 + ro);
    }
#pragma unroll
    for (int ct = 0; ct < CT; ++ct) {
      size_t ro = (size_t)(obase + ct * 16 + lr) * D + kt + lk * 8;
      b0[ct] = *reinterpret_cast<const h8v*>(W0 + ro);
      b1[ct] = *reinterpret_cast<const h8v*>(W1 + ro);
    }
#pragma unroll
    for (int rt = 0; rt < RT; ++rt)
#pragma unroll
      for (int ct = 0; ct < CT; ++ct) {
        acc[rt][ct] = __builtin_amdgcn_mfma_f32_16x16x32_f16(a0[rt], b0[ct], acc[rt][ct], 0, 0, 0);
        acc[rt][ct] = __builtin_amdgcn_mfma_f32_16x16x32_f16(a0[rt], b1[ct], acc[rt][ct], 0, 0, 0);
        acc[rt][ct] = __builtin_amdgcn_mfma_f32_16x16x32_f16(a1[rt], b0[ct], acc[rt][ct], 0, 0, 0);
      }
  }
#pragma unroll
  for (int rt = 0; rt < RT; ++rt)
#pragma unroll
    for (int ct = 0; ct < CT; ++ct) {
      int orow = obase + ct * 16 + lr;
      if (orow < O) {
        float s = aS[orow], bb = aB[orow];
#pragma unroll
        for (int r = 0; r < 4; ++r) {
          int n = nbase + rt * 16 + lk * 4 + r;
          Ob[(size_t)orow * N + n] = acc[rt][ct][r] * s + bb;
        }
      }
    }
}

// ---------------- LIF on PRE + bf16 spike copy (fp32 write only for router rows) ------------
__global__ __launch_bounds__(256) void lif_pre(float* __restrict__ p, ushort_t* __restrict__ spkb)
{
  int j = blockIdx.x * 256 + threadIdx.x;
  bool keepf = (blockIdx.x >= 480 && blockIdx.x < 484);   // router rows need fp32 spikes
  int b = blockIdx.y;
  float mem = 0.0f;
#pragma unroll
  for (int t = 0; t < 4; ++t) {
    size_t idx = (size_t)(t * 8 + b) * ((size_t)ROWS * N) + j;
    float x = p[idx];
    mem += (x - mem) * 0.5f;
    bool fire = (mem >= 1.0f);
    if (keepf) p[idx] = fire ? 1.0f : 0.0f;
    spkb[idx] = fire ? (ushort_t)0x3F80 : (ushort_t)0;
    mem = fire ? 0.0f : mem;
  }
}

// ---------------- generic LIF (in place) ----------------
__global__ __launch_bounds__(256) void lif_kernel(float* __restrict__ p, int FN)
{
  int j = blockIdx.x * 256 + threadIdx.x;
  int yb = blockIdx.y; int b = yb & 7; int e = yb >> 3;
  float mem = 0.0f;
#pragma unroll
  for (int t = 0; t < 4; ++t) {
    size_t idx = (size_t)(e * 32 + t * 8 + b) * FN + j;
    float x = p[idx];
    mem += (x - mem) * 0.5f;
    float sp = (mem >= 1.0f) ? 1.0f : 0.0f;
    p[idx] = sp;
    mem = (sp != 0.0f) ? 0.0f : mem;
  }
}

// ---------------- transpose spikes: SPKB[tb][base+ey*96+c][n] -> dst[ey*32+tb][n][c] --------
__global__ __launch_bounds__(256) void transpose_spk(
    const ushort_t* __restrict__ SPKB, ushort_t* __restrict__ dst, int srcBase)
{
  __shared__ ushort_t tile[32][33];
  int z = blockIdx.z, tb = z & 31, ey = z >> 5;
  const ushort_t* src = SPKB + ((size_t)tb * ROWS + srcBase + ey * 96) * N;
  ushort_t* d = dst + (size_t)z * N * 96;
  int n0 = blockIdx.x * 32, c0 = blockIdx.y * 32;
  int t = threadIdx.x, nn = t & 31, cs = t >> 5;
#pragma unroll
  for (int l = 0; l < 4; ++l) {
    int cc = cs + 8 * l;
    tile[cc][nn] = src[(size_t)(c0 + cc) * N + n0 + nn];
  }
  __syncthreads();
  int cc2 = t & 31, ns = t >> 5;
#pragma unroll
  for (int l = 0; l < 4; ++l) {
    int nn2 = ns + 8 * l;
    d[(size_t)(n0 + nn2) * 96 + c0 + cc2] = tile[cc2][nn2];
  }
}

// ---------------- attn[bi][n][m] = sum_c QT[bi][n][c]*KT[tb][m][c] (bf16 MFMA, exact) -------
__global__ __launch_bounds__(256) void attn_mfma(
    const ushort_t* __restrict__ QT, const ushort_t* __restrict__ KT, ushort_t* __restrict__ ATTNB)
{
  int bi = blockIdx.y, tb = bi & 31;
  const ushort_t* q  = QT + (size_t)bi * N * 96;
  const ushort_t* kk = KT + (size_t)tb * N * 96;
  ushort_t* ob = ATTNB + (size_t)bi * N * N;
  int m0 = blockIdx.x * 128;
  int t = threadIdx.x, w = t >> 6, l = t & 63;
  int lr = l & 15, lk = l >> 4;
  int nb = w * 64;
  f4v acc[4][8] = {};
  for (int kt = 0; kt < 96; kt += 32) {
    bf8v a[4], b[8];
#pragma unroll
    for (int rt = 0; rt < 4; ++rt)
      a[rt] = *reinterpret_cast<const bf8v*>(q + (size_t)(nb + rt * 16 + lr) * 96 + kt + lk * 8);
#pragma unroll
    for (int ct = 0; ct < 8; ++ct)
      b[ct] = *reinterpret_cast<const bf8v*>(kk + (size_t)(m0 + ct * 16 + lr) * 96 + kt + lk * 8);
#pragma unroll
    for (int rt = 0; rt < 4; ++rt)
#pragma unroll
      for (int ct = 0; ct < 8; ++ct)
        acc[rt][ct] = __builtin_amdgcn_mfma_f32_16x16x32_bf16(a[rt], b[ct], acc[rt][ct], 0, 0, 0);
  }
#pragma unroll
  for (int rt = 0; rt < 4; ++rt)
#pragma unroll
    for (int ct = 0; ct < 8; ++ct)
#pragma unroll
      for (int r = 0; r < 4; ++r) {
        int n = nb + rt * 16 + lk * 4 + r;
        int m = m0 + ct * 16 + lr;
        float v = acc[rt][ct][r];   // exact int <= 96
        ob[(size_t)n * N + m] = (ushort_t)(__builtin_bit_cast(unsigned, v) >> 16);
      }
}

// ---------------- res[bi][n][d] = sum_m ATTNB[bi][n][m]*v[tb][d][m] (bf16 MFMA, exact) ------
__global__ __launch_bounds__(256) void res_mfma(
    const ushort_t* __restrict__ ATTNB, const ushort_t* __restrict__ SPKB, float* __restrict__ RES)
{
  int bi = blockIdx.y, tb = bi & 31;
  const ushort_t* A = ATTNB + (size_t)bi * N * N;
  const ushort_t* V = SPKB + ((size_t)tb * ROWS + 96) * N;
  float* ob = RES + (size_t)bi * N * C;
  int d0 = blockIdx.x * 96;
  int t = threadIdx.x, w = t >> 6, l = t & 63;
  int lr = l & 15, lk = l >> 4;
  int nb = w * 64;
  f4v acc[4][6] = {};
  for (int kt = 0; kt < 256; kt += 32) {
    bf8v a[4], b[6];
#pragma unroll
    for (int rt = 0; rt < 4; ++rt)
      a[rt] = *reinterpret_cast<const bf8v*>(A + (size_t)(nb + rt * 16 + lr) * N + kt + lk * 8);
#pragma unroll
    for (int ct = 0; ct < 6; ++ct)
      b[ct] = *reinterpret_cast<const bf8v*>(V + (size_t)(d0 + ct * 16 + lr) * N + kt + lk * 8);
#pragma unroll
    for (int rt = 0; rt < 4; ++rt)
#pragma unroll
      for (int ct = 0; ct < 6; ++ct)
        acc[rt][ct] = __builtin_amdgcn_mfma_f32_16x16x32_bf16(a[rt], b[ct], acc[rt][ct], 0, 0, 0);
  }
#pragma unroll
  for (int rt = 0; rt < 4; ++rt)
#pragma unroll
    for (int ct = 0; ct < 6; ++ct)
#pragma unroll
      for (int r = 0; r < 4; ++r) {
        int n = nb + rt * 16 + lk * 4 + r;
        int d = d0 + ct * 16 + lr;
        ob[(size_t)n * C + d] = acc[rt][ct][r];
      }
}

// ---------------- y[tb,d,n] = sum_e w[tb,e,n]*res_spk[e,tb,n,d] ----------------
__global__ __launch_bounds__(1024) void y_kernel(
    const float* __restrict__ SPK, const float* __restrict__ RES, float* __restrict__ Y)
{
  __shared__ float tile[32][33];
  int tb = blockIdx.z;
  int d0 = blockIdx.y * 32, n0 = blockIdx.x * 32;
  int tx = threadIdx.x, ty = threadIdx.y;
  int n = n0 + ty, d = d0 + tx;
  const float* wrow = SPK + (size_t)tb * ROWS * N + 480 * N;
  float v = 0.0f;
#pragma unroll
  for (int e = 0; e < 4; ++e) {
    float w = wrow[e * N + n];
    float r = RES[((size_t)(e * TB + tb) * N + n) * C + d];
    v += w * r;
  }
  tile[ty][tx] = v;
  __syncthreads();
  Y[(size_t)tb * C * N + (size_t)(d0 + ty) * N + n0 + tx] = tile[tx][ty];
}

// ---------------- LIF(pp) + residual: out = x + spike ----------------
__global__ __launch_bounds__(256) void lif_addx(
    const float* __restrict__ pp, const float* __restrict__ xin, float* __restrict__ out)
{
  int j = blockIdx.x * 256 + threadIdx.x;
  int b = blockIdx.y;
  float mem = 0.0f;
#pragma unroll
  for (int t = 0; t < 4; ++t) {
    size_t idx = (size_t)(t * 8 + b) * (C * N) + j;
    float x = pp[idx];
    mem += (x - mem) * 0.5f;
    float sp = (mem >= 1.0f) ? 1.0f : 0.0f;
    out[idx] = xin[idx] + sp;
    mem = (sp != 0.0f) ? 0.0f : mem;
  }
}

// ---------------- depthwise 3x3 + BN + LIF + gate ----------------
__global__ __launch_bounds__(256) void dwconv_kernel(
    const float* __restrict__ H, const float* __restrict__ DW,
    const float* __restrict__ aS, const float* __restrict__ aB, float* __restrict__ M)
{
  int u = blockIdx.x * 256 + threadIdx.x;
  int n = u & 255;
  int ch = (u >> 8) & 1023;
  int b = u >> 18;
  int px = n & 15, py = n >> 4;
  float w[9];
#pragma unroll
  for (int i = 0; i < 9; ++i) w[i] = DW[ch * 9 + i];
  float s = aS[ch], bb = aB[ch];
  float mem = 0.0f;
#pragma unroll
  for (int t = 0; t < 4; ++t) {
    const float* hp = H + ((size_t)(t * 8 + b) * HID + ch) * N;
    float acc = 0.0f;
#pragma unroll
    for (int dy = 0; dy < 3; ++dy) {
      int yy = py + dy - 1;
      if (yy < 0 || yy > 15) continue;
#pragma unroll
      for (int dx = 0; dx < 3; ++dx) {
        int xx = px + dx - 1;
        if (xx < 0 || xx > 15) continue;
        acc += hp[yy * 16 + xx] * w[dy * 3 + dx];
      }
    }
    float z = acc * s + bb;
    mem += (z - mem) * 0.5f;
    float sp = (mem >= 1.0f) ? 1.0f : 0.0f;
    mem = (sp != 0.0f) ? 0.0f : mem;
    float x2 = H[((size_t)(t * 8 + b) * HID + HH + ch) * N + n];
    M[((size_t)(t * 8 + b) * HH + ch) * N + n] = sp * x2;
  }
}

// ---------------- final: out += lif(f2) ----------------
__global__ __launch_bounds__(256) void lif_accum(const float* __restrict__ f2, float* __restrict__ out)
{
  int j = blockIdx.x * 256 + threadIdx.x;
  int b = blockIdx.y;
  float mem = 0.0f;
#pragma unroll
  for (int t = 0; t < 4; ++t) {
    size_t idx = (size_t)(t * 8 + b) * (C * N) + j;
    float x = f2[idx];
    mem += (x - mem) * 0.5f;
    float sp = (mem >= 1.0f) ? 1.0f : 0.0f;
    out[idx] += sp;
    mem = (sp != 0.0f) ? 0.0f : mem;
  }
}

} // namespace

extern "C" void kernel_launch(void* const* d_in, const int* in_sizes, int n_in,
                              void* d_out, int out_size, void* d_ws, size_t ws_size,
                              hipStream_t stream)
{
  const float* x         = (const float*)d_in[0];
  const float* k_w       = (const float*)d_in[2];
  const float* v_w       = (const float*)d_in[3];
  const float* router_w  = (const float*)d_in[4];
  const float* router_b  = (const float*)d_in[5];
  const float* router_g  = (const float*)d_in[6];
  const float* router_be = (const float*)d_in[7];
  const float* exp_w     = (const float*)d_in[8];
  const float* exp_g     = (const float*)d_in[9];
  const float* exp_b     = (const float*)d_in[10];
  const float* proj_w    = (const float*)d_in[11];
  const float* proj_b    = (const float*)d_in[12];
  const float* proj_g    = (const float*)d_in[13];
  const float* proj_be   = (const float*)d_in[14];
  const float* fc1_w     = (const float*)d_in[15];
  const float* fc1_b     = (const float*)d_in[16];
  const float* fc1_g     = (const float*)d_in[17];
  const float* fc1_be    = (const float*)d_in[18];
  const float* dw_w      = (const float*)d_in[19];
  const float* dw_b      = (const float*)d_in[20];
  const float* dw_g      = (const float*)d_in[21];
  const float* dw_be     = (const float*)d_in[22];
  const float* fc2_w     = (const float*)d_in[23];
  const float* fc2_b     = (const float*)d_in[24];
  const float* fc2_g     = (const float*)d_in[25];
  const float* fc2_be    = (const float*)d_in[26];

  float* ws  = (float*)d_ws;
  float* out = (float*)d_out;
  ushort_t* spkb = (ushort_t*)(ws + O_SPKB);
  ushort_t* qt   = (ushort_t*)(ws + O_QT);
  ushort_t* ktb  = (ushort_t*)(ws + O_KT);
  ushort_t* attb = (ushort_t*)(ws + O_ATTNB);
  half_t* wpre0 = (half_t*)(ws + O_WPRE0),  *wpre1 = (half_t*)(ws + O_WPRE1);
  half_t* wprj0 = (half_t*)(ws + O_WPROJ0), *wprj1 = (half_t*)(ws + O_WPROJ1);
  half_t* wf10  = (half_t*)(ws + O_WFC10),  *wf11  = (half_t*)(ws + O_WFC11);
  half_t* wf20  = (half_t*)(ws + O_WFC20),  *wf21  = (half_t*)(ws + O_WFC21);
  half_t* xtpre0 = (half_t*)(ws + O_XTPRE), *xtpre1 = xtpre0 + (size_t)TB * N * C;
  half_t* xtprj0 = (half_t*)(ws + O_XTPROJ), *xtprj1 = xtprj0 + (size_t)TB * N * C;
  half_t* xtf10  = (half_t*)(ws + O_XTFC1), *xtf11 = xtf10 + (size_t)TB * N * C;
  half_t* xtf20  = (half_t*)(ws + O_XTFC2), *xtf21 = xtf20 + (size_t)TB * N * HH;
  dim3 blk(256);

  // weight pack + folded BN affines
  pack_kernel<<<1302, blk, 0, stream>>>(k_w, v_w, router_w, router_b, router_g, router_be,
                                        exp_w, exp_g, exp_b,
                                        ws + O_WPACK, ws + O_A1S, ws + O_A1B);
  aff_kernel<<<2, blk, 0, stream>>>(proj_g, proj_b, proj_be, ws + O_APS, ws + O_APB, 384);
  aff_kernel<<<8, blk, 0, stream>>>(fc1_g, fc1_b, fc1_be, ws + O_AHS, ws + O_AHB, 2048);
  aff_kernel<<<4, blk, 0, stream>>>(dw_g, dw_b, dw_be, ws + O_ADS, ws + O_ADB, 1024);
  aff_kernel<<<2, blk, 0, stream>>>(fc2_g, fc2_b, fc2_be, ws + O_AFS, ws + O_AFB, 384);

  // fp32 -> fp16 split weights
  split_w<<<1344, blk, 0, stream>>>(ws + O_WPACK, wpre0, wpre1, 868, 896, 384);
  split_w<<<576,  blk, 0, stream>>>(proj_w, wprj0, wprj1, 384, 384, 384);
  split_w<<<3072, blk, 0, stream>>>(fc1_w,  wf10,  wf11,  2048, 2048, 384);
  split_w<<<1536, blk, 0, stream>>>(fc2_w,  wf20,  wf21,  384, 384, 1024);

  // pre projections: split(x) -> sgemm -> PRE
  split_xt<<<dim3(8, 12, 32), blk, 0, stream>>>(x, xtpre0, xtpre1, C);
  sgemm<4, 4><<<dim3(2, 7, 32), blk, 0, stream>>>(xtpre0, xtpre1, wpre0, wpre1,
                                                  ws + O_PRE, ws + O_A1S, ws + O_A1B, 868, C);
  lif_pre<<<dim3(ROWS, 8), blk, 0, stream>>>(ws + O_PRE, spkb);

  // attn path (exact bf16 MFMA) — unchanged
  transpose_spk<<<dim3(8, 3, 32),  blk, 0, stream>>>(spkb, ktb, 0);
  transpose_spk<<<dim3(8, 3, 128), blk, 0, stream>>>(spkb, qt, 484);
  attn_mfma<<<dim3(2, 128), blk, 0, stream>>>(qt, ktb, attb);
  res_mfma<<<dim3(4, 128), blk, 0, stream>>>(attb, spkb, ws + O_RES);
  lif_kernel<<<dim3(N * C / 256, 32), blk, 0, stream>>>(ws + O_RES, N * C);
  y_kernel<<<dim3(8, 12, 32), dim3(32, 32), 0, stream>>>(ws + O_PRE, ws + O_RES, ws + O_Y);

  // proj: split(Y) -> sgemm -> PP, then out = x + lif(PP)
  split_xt<<<dim3(8, 12, 32), blk, 0, stream>>>(ws + O_Y, xtprj0, xtprj1, C);
  sgemm<2, 4><<<dim3(4, 3, 32), blk, 0, stream>>>(xtprj0, xtprj1, wprj0, wprj1,
                                                  ws + O_PP, ws + O_APS, ws + O_APB, 384, C);
  lif_addx<<<dim3(384, 8), blk, 0, stream>>>(ws + O_PP, x, out);

  // fc1: split(out) -> sgemm -> H
  split_xt<<<dim3(8, 12, 32), blk, 0, stream>>>(out, xtf10, xtf11, C);
  sgemm<4, 4><<<dim3(2, 16, 32), blk, 0, stream>>>(xtf10, xtf11, wf10, wf11,
                                                   ws + O_H, ws + O_AHS, ws + O_AHB, HID, C);
  lif_kernel<<<dim3(HID * N / 256, 8), blk, 0, stream>>>(ws + O_H, HID * N);
  // depthwise conv + BN + LIF + gate
  dwconv_kernel<<<dim3(8 * HH * N / 256), blk, 0, stream>>>(ws + O_H, dw_w,
                                                            ws + O_ADS, ws + O_ADB, ws + O_M);
  // fc2: split(M) -> sgemm -> F2, then out += lif(F2)
  split_xt<<<dim3(8, 32, 32), blk, 0, stream>>>(ws + O_M, xtf20, xtf21, HH);
  sgemm<2, 4><<<dim3(4, 3, 32), blk, 0, stream>>>(xtf20, xtf21, wf20, wf21,
                                                  ws + O_F2, ws + O_AFS, ws + O_AFB, 384, HH);
  lif_accum<<<dim3(384, 8), blk, 0, stream>>>(ws + O_F2, out);
}

// Round 7
// 524.803 us; speedup vs baseline: 1.7841x; 1.1254x over previous
//
#include <hip/hip_runtime.h>
#include <cstdint>
#include <cstddef>

namespace {

typedef unsigned short ushort_t;
typedef _Float16 half_t;
typedef __attribute__((ext_vector_type(8))) short bf8v;     // 8 bf16
typedef __attribute__((ext_vector_type(8))) _Float16 h8v;   // 8 fp16
typedef __attribute__((ext_vector_type(4))) float f4v;      // MFMA acc

constexpr float BNS = 0.99999500003749973f; // 1/sqrt(1+1e-5)

constexpr int TB = 32;
constexpr int C  = 384;
constexpr int N  = 256;
constexpr int ROWS = 868;   // 96 k + 384 v + 4 router + 384 q
constexpr int HID = 2048;
constexpr int HH  = 1024;

// ---- workspace layout (float units) ----
constexpr size_t O_A1S  = 0;         // 896 (padded)
constexpr size_t O_A1B  = 896;
constexpr size_t O_APS  = 1792;
constexpr size_t O_APB  = 2176;
constexpr size_t O_AHS  = 2560;
constexpr size_t O_AHB  = 4608;
constexpr size_t O_ADS  = 6656;
constexpr size_t O_ADB  = 7680;
constexpr size_t O_AFS  = 8704;
constexpr size_t O_AFB  = 9088;
constexpr size_t O_DWT  = 9472;      // 9216 fp32 transposed dw weights
constexpr size_t O_WPRE0 = 18688;    // 896x384 half
constexpr size_t O_WPRE1 = 190720;
constexpr size_t O_WPRJ0 = 362752;   // 384x384
constexpr size_t O_WPRJ1 = 436480;
constexpr size_t O_WF10  = 510208;   // 2048x384
constexpr size_t O_WF11  = 903424;
constexpr size_t O_WF20  = 1296640;  // 384x1024
constexpr size_t O_WF21  = 1493248;
constexpr size_t O_WPACK = 1689856;  // fp32 868x384 (dead after split_w)
constexpr size_t O_XTPRE = 2023168;  // half x2 [32][256][384]
constexpr size_t O_SPKB  = 5168896;  // bf16 [32][868][256]
constexpr size_t O_QT    = 8724224;  // bf16 [128][256][96]
constexpr size_t O_KT    = 10297088; // bf16 [32][256][96]
constexpr size_t O_ATTNB = 10690304; // bf16 [128][256][256]
constexpr size_t O_RES   = 14884608; // fp32 [128][256][384]
constexpr size_t O_YT    = O_WPACK;  // fp16 [32][256][384] (WPACK/XTPRE dead)
constexpr size_t O_XF0   = O_QT;     // fp16 [32][256][384] (QT dead)
constexpr size_t O_XF1   = O_ATTNB;  // fp16 (ATTNB dead)
constexpr size_t O_H     = O_RES;    // fp16 [32][256][2048] (RES dead)
constexpr size_t O_M     = 23273216; // fp16 [32][256][1024] -> ends 27467520

// ---------------- pack weights + affines (affines padded to 896) ----------------
__global__ __launch_bounds__(256) void pack_kernel(
    const float* __restrict__ kw, const float* __restrict__ vw,
    const float* __restrict__ rw, const float* __restrict__ rb,
    const float* __restrict__ rg, const float* __restrict__ rbe,
    const float* __restrict__ ew, const float* __restrict__ eg,
    const float* __restrict__ eb,
    float* __restrict__ WP, float* __restrict__ a1s, float* __restrict__ a1b)
{
  int u = blockIdx.x * 256 + threadIdx.x;
  if (u < ROWS * C) {
    int r = u / C, d = u % C;
    float w;
    if (r < 96)       w = kw[r * C + d];
    else if (r < 480) w = vw[(r - 96) * C + d];
    else if (r < 484) w = rw[(r - 480) * C + d];
    else              w = ew[(r - 484) * C + d];
    WP[u] = w;
  }
  if (u < 896) {
    float s, b;
    if (u < 480)      { s = 1.0f; b = 0.0f; }
    else if (u < 484) { int e = u - 480; s = rg[e] * BNS; b = rb[e] * rg[e] * BNS + rbe[e]; }
    else if (u < 868) { int j = u - 484; s = eg[j] * BNS; b = eb[j]; }
    else              { s = 0.0f; b = 0.0f; }
    a1s[u] = s; a1b[u] = b;
  }
}

__global__ __launch_bounds__(256) void aff_kernel(
    const float* __restrict__ g, const float* __restrict__ bias,
    const float* __restrict__ be, float* __restrict__ s, float* __restrict__ b, int n)
{
  int u = blockIdx.x * 256 + threadIdx.x;
  if (u < n) { s[u] = g[u] * BNS; b[u] = bias[u] * g[u] * BNS + be[u]; }
}

__global__ __launch_bounds__(256) void dwt_kernel(const float* __restrict__ dw, float* __restrict__ dwt)
{
  int u = blockIdx.x * 256 + threadIdx.x;
  if (u < HH * 9) { int ch = u / 9, i = u % 9; dwt[i * HH + ch] = dw[u]; }
}

// ---------------- fp32 -> 2x fp16 weight split, zero-padded rows ----------------
__global__ __launch_bounds__(256) void split_w(
    const float* __restrict__ W, half_t* __restrict__ W0, half_t* __restrict__ W1,
    int O, int Opad, int D)
{
  int u = blockIdx.x * 256 + threadIdx.x;
  if (u >= Opad * D) return;
  int r = u / D;
  float v = (r < O) ? W[u] : 0.0f;
  half_t h0 = (half_t)v;
  half_t h1 = (half_t)(v - (float)h0);
  W0[u] = h0; W1[u] = h1;
}

// ---------------- X [tb][D][N] fp32 -> XT0,XT1 [tb][N][D] fp16 (transpose + split) ----------
__global__ __launch_bounds__(256) void split_xt(
    const float* __restrict__ X, half_t* __restrict__ X0, half_t* __restrict__ X1, int D)
{
  __shared__ float tile[32][33];
  int tb = blockIdx.z, n0 = blockIdx.x * 32, d0 = blockIdx.y * 32;
  const float* src = X + (size_t)tb * D * N;
  int t = threadIdx.x;
  int nn = t & 31, ds = t >> 5;
#pragma unroll
  for (int l = 0; l < 4; ++l) {
    int dd = ds + 8 * l;
    tile[dd][nn] = src[(size_t)(d0 + dd) * N + n0 + nn];
  }
  __syncthreads();
  int dd2 = t & 31, ns = t >> 5;
#pragma unroll
  for (int l = 0; l < 4; ++l) {
    int nn2 = ns + 8 * l;
    float v = tile[dd2][nn2];
    half_t h0 = (half_t)v;
    half_t h1 = (half_t)(v - (float)h0);
    size_t o = ((size_t)tb * N + n0 + nn2) * D + d0 + dd2;
    X0[o] = h0; X1[o] = h1;
  }
}

// ======= fused split-fp16 MFMA GEMM + BN + LIF epilogue =======
// grid: x = n-tile (64), y = o-tile (64), z = b (8). All 4 time steps in-register.
// MODE 0 (PRE):  dst = spkb bf16 [tb][868][n]
// MODE 1 (PROJ): dst = out fp32 [tb][O][n] = xin + spike
// MODE 2 (FC1):  dst = H fp16 NHWC [tb][n][O]
// MODE 3 (FC2):  dst = out fp32 [tb][O][n] += spike
template<int NPROD, int MODE>
__global__ __launch_bounds__(256) void sgemm_lif(
    const half_t* __restrict__ X0, const half_t* __restrict__ X1,
    const half_t* __restrict__ W0, const half_t* __restrict__ W1,
    const float* __restrict__ aS, const float* __restrict__ aB,
    const float* __restrict__ xin, void* __restrict__ dst,
    int O, int D)
{
  __shared__ ushort_t lsu[64][72];
  __shared__ float lsf[64][68];
  int b = blockIdx.z;
  int n0 = blockIdx.x * 64, o0 = blockIdx.y * 64;
  int tid = threadIdx.x, w = tid >> 6, l = tid & 63;
  int lr = l & 15, lk = l >> 4;
  int wn = w & 1, wo = w >> 1;
  f4v acc[4][2][2] = {};   // [t][rt][ct]
  for (int kt = 0; kt < D; kt += 32) {
    h8v b0[2], b1[2];
#pragma unroll
    for (int ct = 0; ct < 2; ++ct) {
      size_t ro = (size_t)(o0 + wo * 32 + ct * 16 + lr) * D + kt + lk * 8;
      b0[ct] = *(const h8v*)(W0 + ro);
      b1[ct] = *(const h8v*)(W1 + ro);
    }
#pragma unroll
    for (int tt = 0; tt < 4; ++tt) {
      h8v a0[2], a1[2];
#pragma unroll
      for (int rt = 0; rt < 2; ++rt) {
        size_t ro = ((size_t)((tt * 8 + b) * N) + n0 + wn * 32 + rt * 16 + lr) * D + kt + lk * 8;
        a0[rt] = *(const h8v*)(X0 + ro);
        if (NPROD == 3) a1[rt] = *(const h8v*)(X1 + ro);
      }
#pragma unroll
      for (int rt = 0; rt < 2; ++rt)
#pragma unroll
        for (int ct = 0; ct < 2; ++ct) {
          acc[tt][rt][ct] = __builtin_amdgcn_mfma_f32_16x16x32_f16(a0[rt], b0[ct], acc[tt][rt][ct], 0, 0, 0);
          acc[tt][rt][ct] = __builtin_amdgcn_mfma_f32_16x16x32_f16(a0[rt], b1[ct], acc[tt][rt][ct], 0, 0, 0);
          if (NPROD == 3)
            acc[tt][rt][ct] = __builtin_amdgcn_mfma_f32_16x16x32_f16(a1[rt], b0[ct], acc[tt][rt][ct], 0, 0, 0);
        }
    }
  }
  // BN + LIF (4 time steps in-register) -> spike bits (bit r*4+t)
  unsigned sb_[2][2];
#pragma unroll
  for (int rt = 0; rt < 2; ++rt)
#pragma unroll
    for (int ct = 0; ct < 2; ++ct) {
      int o = o0 + wo * 32 + ct * 16 + lr;
      float s = aS[o], bb = aB[o];
      unsigned bits = 0;
#pragma unroll
      for (int r = 0; r < 4; ++r) {
        float mem = 0.0f;
#pragma unroll
        for (int tt = 0; tt < 4; ++tt) {
          float z = acc[tt][rt][ct][r] * s + bb;
          mem += (z - mem) * 0.5f;
          if (mem >= 1.0f) { bits |= 1u << (r * 4 + tt); mem = 0.0f; }
        }
      }
      sb_[rt][ct] = bits;
    }
  // LDS bounce + cooperative coalesced store, one pass per time step
  for (int tt = 0; tt < 4; ++tt) {
    __syncthreads();
#pragma unroll
    for (int rt = 0; rt < 2; ++rt)
#pragma unroll
      for (int ct = 0; ct < 2; ++ct) {
        int ol = wo * 32 + ct * 16 + lr;
#pragma unroll
        for (int r = 0; r < 4; ++r) {
          int nl = wn * 32 + rt * 16 + lk * 4 + r;
          bool fire = (sb_[rt][ct] >> (r * 4 + tt)) & 1;
          if (MODE == 0)      lsu[ol][nl] = fire ? (ushort_t)0x3F80 : (ushort_t)0;
          else if (MODE == 2) lsu[nl][ol] = fire ? (ushort_t)0x3C00 : (ushort_t)0;
          else                lsf[ol][nl] = fire ? 1.0f : 0.0f;
        }
      }
    __syncthreads();
    int tb = tt * 8 + b;
    int row = tid >> 2, cb = (tid & 3) * 16;
    if (MODE == 0) {
      if (o0 + row < O) {
        ushort_t* dp = (ushort_t*)dst + ((size_t)tb * 868 + o0 + row) * 256 + n0 + cb;
        *(uint4*)dp       = *(uint4*)&lsu[row][cb];
        *((uint4*)dp + 1) = *(uint4*)&lsu[row][cb + 8];
      }
    } else if (MODE == 2) {
      half_t* dp = (half_t*)dst + ((size_t)tb * 256 + n0 + row) * (size_t)O + o0 + cb;
      *(uint4*)dp       = *(uint4*)&lsu[row][cb];
      *((uint4*)dp + 1) = *(uint4*)&lsu[row][cb + 8];
    } else if (MODE == 1) {
      float* op = (float*)dst + ((size_t)tb * O + o0 + row) * 256 + n0 + cb;
      const float* xp = xin + ((size_t)tb * O + o0 + row) * 256 + n0 + cb;
#pragma unroll
      for (int j = 0; j < 4; ++j) {
        float4 sv = *(float4*)&lsf[row][cb + j * 4];
        float4 xv = *(const float4*)(xp + j * 4);
        float4 ov = {xv.x + sv.x, xv.y + sv.y, xv.z + sv.z, xv.w + sv.w};
        *(float4*)(op + j * 4) = ov;
      }
    } else {
      float* op = (float*)dst + ((size_t)tb * O + o0 + row) * 256 + n0 + cb;
#pragma unroll
      for (int j = 0; j < 4; ++j) {
        float4 sv = *(float4*)&lsf[row][cb + j * 4];
        float4 ov = *(float4*)(op + j * 4);
        ov.x += sv.x; ov.y += sv.y; ov.z += sv.z; ov.w += sv.w;
        *(float4*)(op + j * 4) = ov;
      }
    }
  }
}

// ---------------- generic LIF (in place), for RES ----------------
__global__ __launch_bounds__(256) void lif_kernel(float* __restrict__ p, int FN)
{
  int j = blockIdx.x * 256 + threadIdx.x;
  int yb = blockIdx.y; int b = yb & 7; int e = yb >> 3;
  float mem = 0.0f;
#pragma unroll
  for (int t = 0; t < 4; ++t) {
    size_t idx = (size_t)(e * 32 + t * 8 + b) * FN + j;
    float x = p[idx];
    mem += (x - mem) * 0.5f;
    float sp = (mem >= 1.0f) ? 1.0f : 0.0f;
    p[idx] = sp;
    mem = (sp != 0.0f) ? 0.0f : mem;
  }
}

// ---------------- transpose spikes: SPKB[tb][base+ey*96+c][n] -> dst[ey*32+tb][n][c] --------
__global__ __launch_bounds__(256) void transpose_spk(
    const ushort_t* __restrict__ SPKB, ushort_t* __restrict__ dst, int srcBase)
{
  __shared__ ushort_t tile[32][33];
  int z = blockIdx.z, tb = z & 31, ey = z >> 5;
  const ushort_t* src = SPKB + ((size_t)tb * ROWS + srcBase + ey * 96) * N;
  ushort_t* d = dst + (size_t)z * N * 96;
  int n0 = blockIdx.x * 32, c0 = blockIdx.y * 32;
  int t = threadIdx.x, nn = t & 31, cs = t >> 5;
#pragma unroll
  for (int l = 0; l < 4; ++l) {
    int cc = cs + 8 * l;
    tile[cc][nn] = src[(size_t)(c0 + cc) * N + n0 + nn];
  }
  __syncthreads();
  int cc2 = t & 31, ns = t >> 5;
#pragma unroll
  for (int l = 0; l < 4; ++l) {
    int nn2 = ns + 8 * l;
    d[(size_t)(n0 + nn2) * 96 + c0 + cc2] = tile[cc2][nn2];
  }
}

// ---------------- attn[bi][n][m] = sum_c QT[bi][n][c]*KT[tb][m][c] (bf16 MFMA, exact) -------
__global__ __launch_bounds__(256) void attn_mfma(
    const ushort_t* __restrict__ QT, const ushort_t* __restrict__ KT, ushort_t* __restrict__ ATTNB)
{
  int bi = blockIdx.y, tb = bi & 31;
  const ushort_t* q  = QT + (size_t)bi * N * 96;
  const ushort_t* kk = KT + (size_t)tb * N * 96;
  ushort_t* ob = ATTNB + (size_t)bi * N * N;
  int m0 = blockIdx.x * 128;
  int t = threadIdx.x, w = t >> 6, l = t & 63;
  int lr = l & 15, lk = l >> 4;
  int nb = w * 64;
  f4v acc[4][8] = {};
  for (int kt = 0; kt < 96; kt += 32) {
    bf8v a[4], b[8];
#pragma unroll
    for (int rt = 0; rt < 4; ++rt)
      a[rt] = *reinterpret_cast<const bf8v*>(q + (size_t)(nb + rt * 16 + lr) * 96 + kt + lk * 8);
#pragma unroll
    for (int ct = 0; ct < 8; ++ct)
      b[ct] = *reinterpret_cast<const bf8v*>(kk + (size_t)(m0 + ct * 16 + lr) * 96 + kt + lk * 8);
#pragma unroll
    for (int rt = 0; rt < 4; ++rt)
#pragma unroll
      for (int ct = 0; ct < 8; ++ct)
        acc[rt][ct] = __builtin_amdgcn_mfma_f32_16x16x32_bf16(a[rt], b[ct], acc[rt][ct], 0, 0, 0);
  }
#pragma unroll
  for (int rt = 0; rt < 4; ++rt)
#pragma unroll
    for (int ct = 0; ct < 8; ++ct)
#pragma unroll
      for (int r = 0; r < 4; ++r) {
        int n = nb + rt * 16 + lk * 4 + r;
        int m = m0 + ct * 16 + lr;
        float v = acc[rt][ct][r];
        ob[(size_t)n * N + m] = (ushort_t)(__builtin_bit_cast(unsigned, v) >> 16);
      }
}

// ---------------- res[bi][n][d] = sum_m ATTNB[bi][n][m]*v[tb][d][m] (bf16 MFMA, exact) ------
__global__ __launch_bounds__(256) void res_mfma(
    const ushort_t* __restrict__ ATTNB, const ushort_t* __restrict__ SPKB, float* __restrict__ RES)
{
  int bi = blockIdx.y, tb = bi & 31;
  const ushort_t* A = ATTNB + (size_t)bi * N * N;
  const ushort_t* V = SPKB + ((size_t)tb * ROWS + 96) * N;
  float* ob = RES + (size_t)bi * N * C;
  int d0 = blockIdx.x * 96;
  int t = threadIdx.x, w = t >> 6, l = t & 63;
  int lr = l & 15, lk = l >> 4;
  int nb = w * 64;
  f4v acc[4][6] = {};
  for (int kt = 0; kt < 256; kt += 32) {
    bf8v a[4], b[6];
#pragma unroll
    for (int rt = 0; rt < 4; ++rt)
      a[rt] = *reinterpret_cast<const bf8v*>(A + (size_t)(nb + rt * 16 + lr) * N + kt + lk * 8);
#pragma unroll
    for (int ct = 0; ct < 6; ++ct)
      b[ct] = *reinterpret_cast<const bf8v*>(V + (size_t)(d0 + ct * 16 + lr) * N + kt + lk * 8);
#pragma unroll
    for (int rt = 0; rt < 4; ++rt)
#pragma unroll
      for (int ct = 0; ct < 6; ++ct)
        acc[rt][ct] = __builtin_amdgcn_mfma_f32_16x16x32_bf16(a[rt], b[ct], acc[rt][ct], 0, 0, 0);
  }
#pragma unroll
  for (int rt = 0; rt < 4; ++rt)
#pragma unroll
    for (int ct = 0; ct < 6; ++ct)
#pragma unroll
      for (int r = 0; r < 4; ++r) {
        int n = nb + rt * 16 + lk * 4 + r;
        int d = d0 + ct * 16 + lr;
        ob[(size_t)n * C + d] = acc[rt][ct][r];
      }
}

// ---------------- YT[tb][n][d] = sum_e w_spk[tb,e,n]*res_spk[e,tb,n,d]  (int 0..4, fp16) ----
__global__ __launch_bounds__(128) void y_kernel(
    const ushort_t* __restrict__ SPKB, const float* __restrict__ RES, half_t* __restrict__ YT)
{
  int d = blockIdx.x * 128 + threadIdx.x;
  int n = blockIdx.y, tb = blockIdx.z;
  float v = 0.0f;
#pragma unroll
  for (int e = 0; e < 4; ++e) {
    ushort_t wu = SPKB[((size_t)tb * ROWS + 480 + e) * 256 + n];
    if (wu) v += RES[(((size_t)(e * 32 + tb) * 256) + n) * 384 + d];
  }
  YT[((size_t)tb * 256 + n) * 384 + d] = (half_t)v;
}

// ---------------- depthwise 3x3 NHWC fp16 + BN + LIF + gate -> M fp16 K-major --------------
__global__ __launch_bounds__(256) void dwconv_nhwc(
    const half_t* __restrict__ H, const float* __restrict__ DWT,
    const float* __restrict__ aS, const float* __restrict__ aB, half_t* __restrict__ M)
{
  int u = blockIdx.x * 256 + threadIdx.x;   // 8 * 256 * 1024
  int ch = u & 1023;
  int n = (u >> 10) & 255;
  int b = u >> 18;
  int px = n & 15, py = n >> 4;
  float w[9];
#pragma unroll
  for (int i = 0; i < 9; ++i) w[i] = DWT[i * HH + ch];
  float s = aS[ch], bb = aB[ch];
  float mem = 0.0f;
#pragma unroll
  for (int t = 0; t < 4; ++t) {
    size_t base = (size_t)(t * 8 + b) * 256;
    float acc = 0.0f;
#pragma unroll
    for (int dy = 0; dy < 3; ++dy) {
      int yy = py + dy - 1;
      if (yy < 0 || yy > 15) continue;
#pragma unroll
      for (int dx = 0; dx < 3; ++dx) {
        int xx = px + dx - 1;
        if (xx < 0 || xx > 15) continue;
        acc += (float)H[(base + yy * 16 + xx) * HID + ch] * w[dy * 3 + dx];
      }
    }
    float z = acc * s + bb;
    mem += (z - mem) * 0.5f;
    float sp = (mem >= 1.0f) ? 1.0f : 0.0f;
    mem = (sp != 0.0f) ? 0.0f : mem;
    float x2 = (float)H[(base + n) * HID + HH + ch];
    M[(base + n) * HH + ch] = (half_t)(sp * x2);
  }
}

} // namespace

extern "C" void kernel_launch(void* const* d_in, const int* in_sizes, int n_in,
                              void* d_out, int out_size, void* d_ws, size_t ws_size,
                              hipStream_t stream)
{
  const float* x         = (const float*)d_in[0];
  const float* k_w       = (const float*)d_in[2];
  const float* v_w       = (const float*)d_in[3];
  const float* router_w  = (const float*)d_in[4];
  const float* router_b  = (const float*)d_in[5];
  const float* router_g  = (const float*)d_in[6];
  const float* router_be = (const float*)d_in[7];
  const float* exp_w     = (const float*)d_in[8];
  const float* exp_g     = (const float*)d_in[9];
  const float* exp_b     = (const float*)d_in[10];
  const float* proj_w    = (const float*)d_in[11];
  const float* proj_b    = (const float*)d_in[12];
  const float* proj_g    = (const float*)d_in[13];
  const float* proj_be   = (const float*)d_in[14];
  const float* fc1_w     = (const float*)d_in[15];
  const float* fc1_b     = (const float*)d_in[16];
  const float* fc1_g     = (const float*)d_in[17];
  const float* fc1_be    = (const float*)d_in[18];
  const float* dw_w      = (const float*)d_in[19];
  const float* dw_b      = (const float*)d_in[20];
  const float* dw_g      = (const float*)d_in[21];
  const float* dw_be     = (const float*)d_in[22];
  const float* fc2_w     = (const float*)d_in[23];
  const float* fc2_b     = (const float*)d_in[24];
  const float* fc2_g     = (const float*)d_in[25];
  const float* fc2_be    = (const float*)d_in[26];

  float* ws  = (float*)d_ws;
  float* out = (float*)d_out;
  ushort_t* spkb = (ushort_t*)(ws + O_SPKB);
  ushort_t* qt   = (ushort_t*)(ws + O_QT);
  ushort_t* ktb  = (ushort_t*)(ws + O_KT);
  ushort_t* attb = (ushort_t*)(ws + O_ATTNB);
  half_t* wpre0 = (half_t*)(ws + O_WPRE0), *wpre1 = (half_t*)(ws + O_WPRE1);
  half_t* wprj0 = (half_t*)(ws + O_WPRJ0), *wprj1 = (half_t*)(ws + O_WPRJ1);
  half_t* wf10  = (half_t*)(ws + O_WF10),  *wf11  = (half_t*)(ws + O_WF11);
  half_t* wf20  = (half_t*)(ws + O_WF20),  *wf21  = (half_t*)(ws + O_WF21);
  half_t* xtpre0 = (half_t*)(ws + O_XTPRE), *xtpre1 = xtpre0 + (size_t)TB * N * C;
  half_t* yt    = (half_t*)(ws + O_YT);
  half_t* xf0   = (half_t*)(ws + O_XF0), *xf1 = (half_t*)(ws + O_XF1);
  half_t* hbuf  = (half_t*)(ws + O_H);
  half_t* mbuf  = (half_t*)(ws + O_M);
  dim3 blk(256);

  // setup: weight pack, affines, dw transpose, fp16 splits
  pack_kernel<<<1302, blk, 0, stream>>>(k_w, v_w, router_w, router_b, router_g, router_be,
                                        exp_w, exp_g, exp_b,
                                        ws + O_WPACK, ws + O_A1S, ws + O_A1B);
  aff_kernel<<<2, blk, 0, stream>>>(proj_g, proj_b, proj_be, ws + O_APS, ws + O_APB, 384);
  aff_kernel<<<8, blk, 0, stream>>>(fc1_g, fc1_b, fc1_be, ws + O_AHS, ws + O_AHB, 2048);
  aff_kernel<<<4, blk, 0, stream>>>(dw_g, dw_b, dw_be, ws + O_ADS, ws + O_ADB, 1024);
  aff_kernel<<<2, blk, 0, stream>>>(fc2_g, fc2_b, fc2_be, ws + O_AFS, ws + O_AFB, 384);
  dwt_kernel<<<36, blk, 0, stream>>>(dw_w, ws + O_DWT);
  split_w<<<1344, blk, 0, stream>>>(ws + O_WPACK, wpre0, wpre1, 868, 896, 384);
  split_w<<<576,  blk, 0, stream>>>(proj_w, wprj0, wprj1, 384, 384, 384);
  split_w<<<3072, blk, 0, stream>>>(fc1_w,  wf10,  wf11,  2048, 2048, 384);
  split_w<<<1536, blk, 0, stream>>>(fc2_w,  wf20,  wf21,  384, 384, 1024);

  // pre projections: split(x) -> fused sgemm+LIF -> spkb (bf16 spikes)
  split_xt<<<dim3(8, 12, 32), blk, 0, stream>>>(x, xtpre0, xtpre1, C);
  sgemm_lif<3, 0><<<dim3(4, 14, 8), blk, 0, stream>>>(
      xtpre0, xtpre1, wpre0, wpre1, ws + O_A1S, ws + O_A1B, nullptr, spkb, 868, C);

  // attn path (exact bf16 MFMA)
  transpose_spk<<<dim3(8, 3, 32),  blk, 0, stream>>>(spkb, ktb, 0);
  transpose_spk<<<dim3(8, 3, 128), blk, 0, stream>>>(spkb, qt, 484);
  attn_mfma<<<dim3(2, 128), blk, 0, stream>>>(qt, ktb, attb);
  res_mfma<<<dim3(4, 128), blk, 0, stream>>>(attb, spkb, ws + O_RES);
  lif_kernel<<<dim3(N * C / 256, 32), blk, 0, stream>>>(ws + O_RES, N * C);
  y_kernel<<<dim3(3, 256, 32), dim3(128), 0, stream>>>(spkb, ws + O_RES, yt);

  // proj: YT fp16 exact (ints 0..4) -> fused sgemm+LIF -> out = x + spike
  sgemm_lif<2, 1><<<dim3(4, 6, 8), blk, 0, stream>>>(
      yt, nullptr, wprj0, wprj1, ws + O_APS, ws + O_APB, x, out, 384, C);

  // fc1: split(out) -> fused sgemm+LIF -> H fp16 NHWC spikes
  split_xt<<<dim3(8, 12, 32), blk, 0, stream>>>(out, xf0, xf1, C);
  sgemm_lif<3, 2><<<dim3(4, 32, 8), blk, 0, stream>>>(
      xf0, xf1, wf10, wf11, ws + O_AHS, ws + O_AHB, nullptr, hbuf, 2048, C);

  // depthwise conv + BN + LIF + gate -> M fp16 (binary, K-major)
  dwconv_nhwc<<<dim3(8192), blk, 0, stream>>>(hbuf, ws + O_DWT, ws + O_ADS, ws + O_ADB, mbuf);

  // fc2: M fp16 exact binary -> fused sgemm+LIF -> out += spike
  sgemm_lif<2, 3><<<dim3(4, 6, 8), blk, 0, stream>>>(
      mbuf, nullptr, wf20, wf21, ws + O_AFS, ws + O_AFB, nullptr, out, 384, HH);
}

// Round 8
// 502.063 us; speedup vs baseline: 1.8649x; 1.0453x over previous
//
#include <hip/hip_runtime.h>
#include <cstdint>
#include <cstddef>

namespace {

typedef unsigned short ushort_t;
typedef _Float16 half_t;
typedef __attribute__((ext_vector_type(8))) short bf8v;     // 8 bf16
typedef __attribute__((ext_vector_type(8))) _Float16 h8v;   // 8 fp16
typedef __attribute__((ext_vector_type(4))) float f4v;      // MFMA acc

constexpr float BNS = 0.99999500003749973f; // 1/sqrt(1+1e-5)

constexpr int TB = 32;
constexpr int C  = 384;
constexpr int N  = 256;
constexpr int ROWS = 868;   // 96 k + 384 v + 4 router + 384 q
constexpr int HID = 2048;
constexpr int HH  = 1024;

// ---- workspace layout (float units) ----
constexpr size_t O_A1S  = 0;         // 896 (padded)
constexpr size_t O_A1B  = 896;
constexpr size_t O_APS  = 1792;
constexpr size_t O_APB  = 2176;
constexpr size_t O_AHS  = 2560;
constexpr size_t O_AHB  = 4608;
constexpr size_t O_ADS  = 6656;
constexpr size_t O_ADB  = 7680;
constexpr size_t O_AFS  = 8704;
constexpr size_t O_AFB  = 9088;
constexpr size_t O_DWT  = 9472;      // 9216 fp32 transposed dw weights
constexpr size_t O_WPRE0 = 18688;    // 896x384 half
constexpr size_t O_WPRE1 = 190720;
constexpr size_t O_WPRJ0 = 362752;   // 384x384
constexpr size_t O_WPRJ1 = 436480;
constexpr size_t O_WF10  = 510208;   // 2048x384
constexpr size_t O_WF11  = 903424;
constexpr size_t O_WF20  = 1296640;  // 384x1024
constexpr size_t O_WF21  = 1493248;
constexpr size_t O_XTPRE = 2023168;  // half x2 [32][256][384]
constexpr size_t O_SPKB  = 5168896;  // bf16 [32][868][256]
constexpr size_t O_QT    = 8724224;  // bf16 [128][256][96]
constexpr size_t O_KT    = 10297088; // bf16 [32][256][96]
constexpr size_t O_ATTNB = 10690304; // bf16 [128][256][256]
constexpr size_t O_RES   = 14884608; // fp32 [128][256][384]
constexpr size_t O_YT    = 1689856;  // fp16 [32][256][384]
constexpr size_t O_XF0   = O_QT;     // fp16 [32][256][384] (QT dead)
constexpr size_t O_XF1   = O_ATTNB;  // fp16 (ATTNB dead)
constexpr size_t O_H     = O_RES;    // fp16 [32][256][2048] (RES dead)
constexpr size_t O_M     = 23273216; // fp16 [32][256][1024] -> ends 27467520

// ---------------- all affines + dw transpose in one launch ----------------
__global__ __launch_bounds__(256) void affines_all(
    const float* __restrict__ rb, const float* __restrict__ rg, const float* __restrict__ rbe,
    const float* __restrict__ eg, const float* __restrict__ eb,
    const float* __restrict__ pg, const float* __restrict__ pb, const float* __restrict__ pbe,
    const float* __restrict__ hg, const float* __restrict__ hb, const float* __restrict__ hbe,
    const float* __restrict__ dg, const float* __restrict__ db, const float* __restrict__ dbe,
    const float* __restrict__ fg, const float* __restrict__ fb, const float* __restrict__ fbe,
    const float* __restrict__ dw, float* __restrict__ ws)
{
  int u = blockIdx.x * 256 + threadIdx.x;
  if (u < 896) {
    float s, b;
    if (u < 480)      { s = 1.0f; b = 0.0f; }
    else if (u < 484) { int e = u - 480; s = rg[e] * BNS; b = rb[e] * rg[e] * BNS + rbe[e]; }
    else if (u < 868) { int j = u - 484; s = eg[j] * BNS; b = eb[j]; }
    else              { s = 0.0f; b = 0.0f; }
    ws[O_A1S + u] = s; ws[O_A1B + u] = b;
  } else if (u < 1280) {
    int j = u - 896;
    ws[O_APS + j] = pg[j] * BNS; ws[O_APB + j] = pb[j] * pg[j] * BNS + pbe[j];
  } else if (u < 3328) {
    int j = u - 1280;
    ws[O_AHS + j] = hg[j] * BNS; ws[O_AHB + j] = hb[j] * hg[j] * BNS + hbe[j];
  } else if (u < 4352) {
    int j = u - 3328;
    ws[O_ADS + j] = dg[j] * BNS; ws[O_ADB + j] = db[j] * dg[j] * BNS + dbe[j];
  } else if (u < 4736) {
    int j = u - 4352;
    ws[O_AFS + j] = fg[j] * BNS; ws[O_AFB + j] = fb[j] * fg[j] * BNS + fbe[j];
  } else if (u < 4736 + HH * 9) {
    int j = u - 4736; int ch = j / 9, i = j % 9;
    ws[O_DWT + i * HH + ch] = dw[j];
  }
}

// ---------------- all fp32 -> 2x fp16 weight splits in one launch ----------------
// ranges: [0,344064) pre-pack(896x384); +147456 proj; +786432 fc1; +393216 fc2(384x1024)
__global__ __launch_bounds__(256) void split_all(
    const float* __restrict__ kw, const float* __restrict__ vw,
    const float* __restrict__ rw, const float* __restrict__ ew,
    const float* __restrict__ pw, const float* __restrict__ f1w, const float* __restrict__ f2w,
    float* __restrict__ ws)
{
  int u = blockIdx.x * 256 + threadIdx.x;
  float v; size_t o0, o1; int idx;
  if (u < 344064) {
    int r = u / 384, d = u - r * 384;
    if (r < 96)       v = kw[r * 384 + d];
    else if (r < 480) v = vw[(r - 96) * 384 + d];
    else if (r < 484) v = rw[(r - 480) * 384 + d];
    else if (r < 868) v = ew[(r - 484) * 384 + d];
    else              v = 0.0f;
    o0 = O_WPRE0; o1 = O_WPRE1; idx = u;
  } else if (u < 491520) {
    idx = u - 344064; v = pw[idx]; o0 = O_WPRJ0; o1 = O_WPRJ1;
  } else if (u < 1277952) {
    idx = u - 491520; v = f1w[idx]; o0 = O_WF10; o1 = O_WF11;
  } else if (u < 1671168) {
    idx = u - 1277952; v = f2w[idx]; o0 = O_WF20; o1 = O_WF21;
  } else return;
  half_t h0 = (half_t)v;
  half_t h1 = (half_t)(v - (float)h0);
  ((half_t*)(ws + o0))[idx] = h0;
  ((half_t*)(ws + o1))[idx] = h1;
}

// ---------------- X [tb][D][N] fp32 -> XT0,XT1 [tb][N][D] fp16 (transpose + split) ----------
__global__ __launch_bounds__(256) void split_xt(
    const float* __restrict__ X, half_t* __restrict__ X0, half_t* __restrict__ X1, int D)
{
  __shared__ float tile[32][33];
  int tb = blockIdx.z, n0 = blockIdx.x * 32, d0 = blockIdx.y * 32;
  const float* src = X + (size_t)tb * D * N;
  int t = threadIdx.x;
  int nn = t & 31, ds = t >> 5;
#pragma unroll
  for (int l = 0; l < 4; ++l) {
    int dd = ds + 8 * l;
    tile[dd][nn] = src[(size_t)(d0 + dd) * N + n0 + nn];
  }
  __syncthreads();
  int dd2 = t & 31, ns = t >> 5;
#pragma unroll
  for (int l = 0; l < 4; ++l) {
    int nn2 = ns + 8 * l;
    float v = tile[dd2][nn2];
    half_t h0 = (half_t)v;
    half_t h1 = (half_t)(v - (float)h0);
    size_t o = ((size_t)tb * N + n0 + nn2) * D + d0 + dd2;
    X0[o] = h0; X1[o] = h1;
  }
}

// ======= fused split-fp16 MFMA GEMM + BN + LIF epilogue =======
// grid: x = n-tile (64), y = o-tile (64), z = b (8). All 4 time steps in-register.
// K-step: ALL loads hoisted ahead of ALL MFMAs (latency batch-hiding).
// MODE 0 (PRE):  dst = spkb bf16 [tb][868][n]
// MODE 1 (PROJ): dst = out fp32 [tb][O][n] = xin + spike
// MODE 2 (FC1):  dst = H fp16 NHWC [tb][n][O]
// MODE 3 (FC2):  dst = out fp32 [tb][O][n] += spike
template<int NPROD, int MODE>
__global__ __launch_bounds__(256) void sgemm_lif(
    const half_t* __restrict__ X0, const half_t* __restrict__ X1,
    const half_t* __restrict__ W0, const half_t* __restrict__ W1,
    const float* __restrict__ aS, const float* __restrict__ aB,
    const float* __restrict__ xin, void* __restrict__ dst,
    int O, int D)
{
  __shared__ ushort_t lsu[64][72];
  __shared__ float lsf[64][68];
  int b = blockIdx.z;
  int n0 = blockIdx.x * 64, o0 = blockIdx.y * 64;
  int tid = threadIdx.x, w = tid >> 6, l = tid & 63;
  int lr = l & 15, lk = l >> 4;
  int wn = w & 1, wo = w >> 1;
  f4v acc[4][2][2] = {};   // [t][rt][ct]
  for (int kt = 0; kt < D; kt += 32) {
    h8v b0[2], b1[2], a0[4][2], a1[4][2];
    // ---- hoisted load phase: every global load of this K-step issues first ----
#pragma unroll
    for (int ct = 0; ct < 2; ++ct) {
      size_t ro = (size_t)(o0 + wo * 32 + ct * 16 + lr) * D + kt + lk * 8;
      b0[ct] = *(const h8v*)(W0 + ro);
      b1[ct] = *(const h8v*)(W1 + ro);
    }
#pragma unroll
    for (int tt = 0; tt < 4; ++tt)
#pragma unroll
      for (int rt = 0; rt < 2; ++rt) {
        size_t ro = ((size_t)((tt * 8 + b) * N) + n0 + wn * 32 + rt * 16 + lr) * D + kt + lk * 8;
        a0[tt][rt] = *(const h8v*)(X0 + ro);
        if (NPROD == 3) a1[tt][rt] = *(const h8v*)(X1 + ro);
      }
    // ---- MFMA burst (same tt,rt,ct,product order as before) ----
#pragma unroll
    for (int tt = 0; tt < 4; ++tt)
#pragma unroll
      for (int rt = 0; rt < 2; ++rt)
#pragma unroll
        for (int ct = 0; ct < 2; ++ct) {
          acc[tt][rt][ct] = __builtin_amdgcn_mfma_f32_16x16x32_f16(a0[tt][rt], b0[ct], acc[tt][rt][ct], 0, 0, 0);
          acc[tt][rt][ct] = __builtin_amdgcn_mfma_f32_16x16x32_f16(a0[tt][rt], b1[ct], acc[tt][rt][ct], 0, 0, 0);
          if (NPROD == 3)
            acc[tt][rt][ct] = __builtin_amdgcn_mfma_f32_16x16x32_f16(a1[tt][rt], b0[ct], acc[tt][rt][ct], 0, 0, 0);
        }
  }
  // BN + LIF (4 time steps in-register) -> spike bits (bit r*4+t)
  unsigned sb_[2][2];
#pragma unroll
  for (int rt = 0; rt < 2; ++rt)
#pragma unroll
    for (int ct = 0; ct < 2; ++ct) {
      int o = o0 + wo * 32 + ct * 16 + lr;
      float s = aS[o], bb = aB[o];
      unsigned bits = 0;
#pragma unroll
      for (int r = 0; r < 4; ++r) {
        float mem = 0.0f;
#pragma unroll
        for (int tt = 0; tt < 4; ++tt) {
          float z = acc[tt][rt][ct][r] * s + bb;
          mem += (z - mem) * 0.5f;
          if (mem >= 1.0f) { bits |= 1u << (r * 4 + tt); mem = 0.0f; }
        }
      }
      sb_[rt][ct] = bits;
    }
  // LDS bounce + cooperative coalesced store, one pass per time step
  for (int tt = 0; tt < 4; ++tt) {
    __syncthreads();
#pragma unroll
    for (int rt = 0; rt < 2; ++rt)
#pragma unroll
      for (int ct = 0; ct < 2; ++ct) {
        int ol = wo * 32 + ct * 16 + lr;
#pragma unroll
        for (int r = 0; r < 4; ++r) {
          int nl = wn * 32 + rt * 16 + lk * 4 + r;
          bool fire = (sb_[rt][ct] >> (r * 4 + tt)) & 1;
          if (MODE == 0)      lsu[ol][nl] = fire ? (ushort_t)0x3F80 : (ushort_t)0;
          else if (MODE == 2) lsu[nl][ol] = fire ? (ushort_t)0x3C00 : (ushort_t)0;
          else                lsf[ol][nl] = fire ? 1.0f : 0.0f;
        }
      }
    __syncthreads();
    int tb = tt * 8 + b;
    int row = tid >> 2, cb = (tid & 3) * 16;
    if (MODE == 0) {
      if (o0 + row < O) {
        ushort_t* dp = (ushort_t*)dst + ((size_t)tb * 868 + o0 + row) * 256 + n0 + cb;
        *(uint4*)dp       = *(uint4*)&lsu[row][cb];
        *((uint4*)dp + 1) = *(uint4*)&lsu[row][cb + 8];
      }
    } else if (MODE == 2) {
      half_t* dp = (half_t*)dst + ((size_t)tb * 256 + n0 + row) * (size_t)O + o0 + cb;
      *(uint4*)dp       = *(uint4*)&lsu[row][cb];
      *((uint4*)dp + 1) = *(uint4*)&lsu[row][cb + 8];
    } else if (MODE == 1) {
      float* op = (float*)dst + ((size_t)tb * O + o0 + row) * 256 + n0 + cb;
      const float* xp = xin + ((size_t)tb * O + o0 + row) * 256 + n0 + cb;
#pragma unroll
      for (int j = 0; j < 4; ++j) {
        float4 sv = *(float4*)&lsf[row][cb + j * 4];
        float4 xv = *(const float4*)(xp + j * 4);
        float4 ov = {xv.x + sv.x, xv.y + sv.y, xv.z + sv.z, xv.w + sv.w};
        *(float4*)(op + j * 4) = ov;
      }
    } else {
      float* op = (float*)dst + ((size_t)tb * O + o0 + row) * 256 + n0 + cb;
#pragma unroll
      for (int j = 0; j < 4; ++j) {
        float4 sv = *(float4*)&lsf[row][cb + j * 4];
        float4 ov = *(float4*)(op + j * 4);
        ov.x += sv.x; ov.y += sv.y; ov.z += sv.z; ov.w += sv.w;
        *(float4*)(op + j * 4) = ov;
      }
    }
  }
}

// ---------------- transpose spikes: SPKB[tb][base+ey*96+c][n] -> dst[ey*32+tb][n][c] --------
__global__ __launch_bounds__(256) void transpose_spk(
    const ushort_t* __restrict__ SPKB, ushort_t* __restrict__ dst, int srcBase)
{
  __shared__ ushort_t tile[32][33];
  int z = blockIdx.z, tb = z & 31, ey = z >> 5;
  const ushort_t* src = SPKB + ((size_t)tb * ROWS + srcBase + ey * 96) * N;
  ushort_t* d = dst + (size_t)z * N * 96;
  int n0 = blockIdx.x * 32, c0 = blockIdx.y * 32;
  int t = threadIdx.x, nn = t & 31, cs = t >> 5;
#pragma unroll
  for (int l = 0; l < 4; ++l) {
    int cc = cs + 8 * l;
    tile[cc][nn] = src[(size_t)(c0 + cc) * N + n0 + nn];
  }
  __syncthreads();
  int cc2 = t & 31, ns = t >> 5;
#pragma unroll
  for (int l = 0; l < 4; ++l) {
    int nn2 = ns + 8 * l;
    d[(size_t)(n0 + nn2) * 96 + c0 + cc2] = tile[cc2][nn2];
  }
}

// ---------------- attn[bi][n][m] = sum_c QT[bi][n][c]*KT[tb][m][c] (bf16 MFMA, exact) -------
__global__ __launch_bounds__(256) void attn_mfma(
    const ushort_t* __restrict__ QT, const ushort_t* __restrict__ KT, ushort_t* __restrict__ ATTNB)
{
  int bi = blockIdx.y, tb = bi & 31;
  const ushort_t* q  = QT + (size_t)bi * N * 96;
  const ushort_t* kk = KT + (size_t)tb * N * 96;
  ushort_t* ob = ATTNB + (size_t)bi * N * N;
  int m0 = blockIdx.x * 128;
  int t = threadIdx.x, w = t >> 6, l = t & 63;
  int lr = l & 15, lk = l >> 4;
  int nb = w * 64;
  f4v acc[4][8] = {};
  for (int kt = 0; kt < 96; kt += 32) {
    bf8v a[4], b[8];
#pragma unroll
    for (int rt = 0; rt < 4; ++rt)
      a[rt] = *reinterpret_cast<const bf8v*>(q + (size_t)(nb + rt * 16 + lr) * 96 + kt + lk * 8);
#pragma unroll
    for (int ct = 0; ct < 8; ++ct)
      b[ct] = *reinterpret_cast<const bf8v*>(kk + (size_t)(m0 + ct * 16 + lr) * 96 + kt + lk * 8);
#pragma unroll
    for (int rt = 0; rt < 4; ++rt)
#pragma unroll
      for (int ct = 0; ct < 8; ++ct)
        acc[rt][ct] = __builtin_amdgcn_mfma_f32_16x16x32_bf16(a[rt], b[ct], acc[rt][ct], 0, 0, 0);
  }
#pragma unroll
  for (int rt = 0; rt < 4; ++rt)
#pragma unroll
    for (int ct = 0; ct < 8; ++ct)
#pragma unroll
      for (int r = 0; r < 4; ++r) {
        int n = nb + rt * 16 + lk * 4 + r;
        int m = m0 + ct * 16 + lr;
        float v = acc[rt][ct][r];
        ob[(size_t)n * N + m] = (ushort_t)(__builtin_bit_cast(unsigned, v) >> 16);
      }
}

// ---------------- res[bi][n][d] = sum_m ATTNB[bi][n][m]*v[tb][d][m] (bf16 MFMA, exact) ------
__global__ __launch_bounds__(256) void res_mfma(
    const ushort_t* __restrict__ ATTNB, const ushort_t* __restrict__ SPKB, float* __restrict__ RES)
{
  int bi = blockIdx.y, tb = bi & 31;
  const ushort_t* A = ATTNB + (size_t)bi * N * N;
  const ushort_t* V = SPKB + ((size_t)tb * ROWS + 96) * N;
  float* ob = RES + (size_t)bi * N * C;
  int d0 = blockIdx.x * 96;
  int t = threadIdx.x, w = t >> 6, l = t & 63;
  int lr = l & 15, lk = l >> 4;
  int nb = w * 64;
  f4v acc[4][6] = {};
  for (int kt = 0; kt < 256; kt += 32) {
    bf8v a[4], b[6];
#pragma unroll
    for (int rt = 0; rt < 4; ++rt)
      a[rt] = *reinterpret_cast<const bf8v*>(A + (size_t)(nb + rt * 16 + lr) * N + kt + lk * 8);
#pragma unroll
    for (int ct = 0; ct < 6; ++ct)
      b[ct] = *reinterpret_cast<const bf8v*>(V + (size_t)(d0 + ct * 16 + lr) * N + kt + lk * 8);
#pragma unroll
    for (int rt = 0; rt < 4; ++rt)
#pragma unroll
      for (int ct = 0; ct < 6; ++ct)
        acc[rt][ct] = __builtin_amdgcn_mfma_f32_16x16x32_bf16(a[rt], b[ct], acc[rt][ct], 0, 0, 0);
  }
#pragma unroll
  for (int rt = 0; rt < 4; ++rt)
#pragma unroll
    for (int ct = 0; ct < 6; ++ct)
#pragma unroll
      for (int r = 0; r < 4; ++r) {
        int n = nb + rt * 16 + lk * 4 + r;
        int d = d0 + ct * 16 + lr;
        ob[(size_t)n * C + d] = acc[rt][ct][r];
      }
}

// ---- fused RES-LIF + router-weighted sum: YT[t*8+b][n][d] = sum_e w_spk*lif(res) ----
__global__ __launch_bounds__(128) void y_lif(
    const ushort_t* __restrict__ SPKB, const float* __restrict__ RES, half_t* __restrict__ YT)
{
  int d = blockIdx.x * 128 + threadIdx.x;
  int n = blockIdx.y, b = blockIdx.z;
  float v[4] = {0.0f, 0.0f, 0.0f, 0.0f};
#pragma unroll
  for (int e = 0; e < 4; ++e) {
    float mem = 0.0f;
#pragma unroll
    for (int t = 0; t < 4; ++t) {
      float r = RES[(((size_t)(e * 32 + t * 8 + b) * 256) + n) * 384 + d];
      mem += (r - mem) * 0.5f;
      if (mem >= 1.0f) {
        mem = 0.0f;
        ushort_t wu = SPKB[((size_t)(t * 8 + b) * ROWS + 480 + e) * 256 + n];
        if (wu) v[t] += 1.0f;
      }
    }
  }
#pragma unroll
  for (int t = 0; t < 4; ++t)
    YT[((size_t)(t * 8 + b) * 256 + n) * 384 + d] = (half_t)v[t];
}

// ---------------- depthwise 3x3 NHWC fp16 + BN + LIF + gate -> M fp16 K-major --------------
__global__ __launch_bounds__(256) void dwconv_nhwc(
    const half_t* __restrict__ H, const float* __restrict__ DWT,
    const float* __restrict__ aS, const float* __restrict__ aB, half_t* __restrict__ M)
{
  int u = blockIdx.x * 256 + threadIdx.x;   // 8 * 256 * 1024
  int ch = u & 1023;
  int n = (u >> 10) & 255;
  int b = u >> 18;
  int px = n & 15, py = n >> 4;
  float w[9];
#pragma unroll
  for (int i = 0; i < 9; ++i) w[i] = DWT[i * HH + ch];
  float s = aS[ch], bb = aB[ch];
  float mem = 0.0f;
#pragma unroll
  for (int t = 0; t < 4; ++t) {
    size_t base = (size_t)(t * 8 + b) * 256;
    float acc = 0.0f;
#pragma unroll
    for (int dy = 0; dy < 3; ++dy) {
      int yy = py + dy - 1;
      if (yy < 0 || yy > 15) continue;
#pragma unroll
      for (int dx = 0; dx < 3; ++dx) {
        int xx = px + dx - 1;
        if (xx < 0 || xx > 15) continue;
        acc += (float)H[(base + yy * 16 + xx) * HID + ch] * w[dy * 3 + dx];
      }
    }
    float z = acc * s + bb;
    mem += (z - mem) * 0.5f;
    float sp = (mem >= 1.0f) ? 1.0f : 0.0f;
    mem = (sp != 0.0f) ? 0.0f : mem;
    float x2 = (float)H[(base + n) * HID + HH + ch];
    M[(base + n) * HH + ch] = (half_t)(sp * x2);
  }
}

} // namespace

extern "C" void kernel_launch(void* const* d_in, const int* in_sizes, int n_in,
                              void* d_out, int out_size, void* d_ws, size_t ws_size,
                              hipStream_t stream)
{
  const float* x         = (const float*)d_in[0];
  const float* k_w       = (const float*)d_in[2];
  const float* v_w       = (const float*)d_in[3];
  const float* router_w  = (const float*)d_in[4];
  const float* router_b  = (const float*)d_in[5];
  const float* router_g  = (const float*)d_in[6];
  const float* router_be = (const float*)d_in[7];
  const float* exp_w     = (const float*)d_in[8];
  const float* exp_g     = (const float*)d_in[9];
  const float* exp_b     = (const float*)d_in[10];
  const float* proj_w    = (const float*)d_in[11];
  const float* proj_b    = (const float*)d_in[12];
  const float* proj_g    = (const float*)d_in[13];
  const float* proj_be   = (const float*)d_in[14];
  const float* fc1_w     = (const float*)d_in[15];
  const float* fc1_b     = (const float*)d_in[16];
  const float* fc1_g     = (const float*)d_in[17];
  const float* fc1_be    = (const float*)d_in[18];
  const float* dw_w      = (const float*)d_in[19];
  const float* dw_b      = (const float*)d_in[20];
  const float* dw_g      = (const float*)d_in[21];
  const float* dw_be     = (const float*)d_in[22];
  const float* fc2_w     = (const float*)d_in[23];
  const float* fc2_b     = (const float*)d_in[24];
  const float* fc2_g     = (const float*)d_in[25];
  const float* fc2_be    = (const float*)d_in[26];

  float* ws  = (float*)d_ws;
  float* out = (float*)d_out;
  ushort_t* spkb = (ushort_t*)(ws + O_SPKB);
  ushort_t* qt   = (ushort_t*)(ws + O_QT);
  ushort_t* ktb  = (ushort_t*)(ws + O_KT);
  ushort_t* attb = (ushort_t*)(ws + O_ATTNB);
  half_t* wpre0 = (half_t*)(ws + O_WPRE0), *wpre1 = (half_t*)(ws + O_WPRE1);
  half_t* wprj0 = (half_t*)(ws + O_WPRJ0), *wprj1 = (half_t*)(ws + O_WPRJ1);
  half_t* wf10  = (half_t*)(ws + O_WF10),  *wf11  = (half_t*)(ws + O_WF11);
  half_t* wf20  = (half_t*)(ws + O_WF20),  *wf21  = (half_t*)(ws + O_WF21);
  half_t* xtpre0 = (half_t*)(ws + O_XTPRE), *xtpre1 = xtpre0 + (size_t)TB * N * C;
  half_t* yt    = (half_t*)(ws + O_YT);
  half_t* xf0   = (half_t*)(ws + O_XF0), *xf1 = (half_t*)(ws + O_XF1);
  half_t* hbuf  = (half_t*)(ws + O_H);
  half_t* mbuf  = (half_t*)(ws + O_M);
  dim3 blk(256);

  // setup: 2 launches
  affines_all<<<55, blk, 0, stream>>>(router_b, router_g, router_be, exp_g, exp_b,
                                      proj_g, proj_b, proj_be, fc1_g, fc1_b, fc1_be,
                                      dw_g, dw_b, dw_be, fc2_g, fc2_b, fc2_be, dw_w, ws);
  split_all<<<6528, blk, 0, stream>>>(k_w, v_w, router_w, exp_w, proj_w, fc1_w, fc2_w, ws);

  // pre projections: split(x) -> fused sgemm+LIF -> spkb (bf16 spikes)
  split_xt<<<dim3(8, 12, 32), blk, 0, stream>>>(x, xtpre0, xtpre1, C);
  sgemm_lif<3, 0><<<dim3(4, 14, 8), blk, 0, stream>>>(
      xtpre0, xtpre1, wpre0, wpre1, ws + O_A1S, ws + O_A1B, nullptr, spkb, 868, C);

  // attn path (exact bf16 MFMA)
  transpose_spk<<<dim3(8, 3, 32),  blk, 0, stream>>>(spkb, ktb, 0);
  transpose_spk<<<dim3(8, 3, 128), blk, 0, stream>>>(spkb, qt, 484);
  attn_mfma<<<dim3(2, 128), blk, 0, stream>>>(qt, ktb, attb);
  res_mfma<<<dim3(4, 128), blk, 0, stream>>>(attb, spkb, ws + O_RES);
  // fused RES-LIF + router sum -> YT fp16 (ints 0..4, exact)
  y_lif<<<dim3(3, 256, 8), dim3(128), 0, stream>>>(spkb, ws + O_RES, yt);

  // proj: YT fp16 exact -> fused sgemm+LIF -> out = x + spike
  sgemm_lif<2, 1><<<dim3(4, 6, 8), blk, 0, stream>>>(
      yt, nullptr, wprj0, wprj1, ws + O_APS, ws + O_APB, x, out, 384, C);

  // fc1: split(out) -> fused sgemm+LIF -> H fp16 NHWC spikes
  split_xt<<<dim3(8, 12, 32), blk, 0, stream>>>(out, xf0, xf1, C);
  sgemm_lif<3, 2><<<dim3(4, 32, 8), blk, 0, stream>>>(
      xf0, xf1, wf10, wf11, ws + O_AHS, ws + O_AHB, nullptr, hbuf, 2048, C);

  // depthwise conv + BN + LIF + gate -> M fp16 (binary, K-major)
  dwconv_nhwc<<<dim3(8192), blk, 0, stream>>>(hbuf, ws + O_DWT, ws + O_ADS, ws + O_ADB, mbuf);

  // fc2: M fp16 exact binary -> fused sgemm+LIF -> out += spike
  sgemm_lif<2, 3><<<dim3(4, 6, 8), blk, 0, stream>>>(
      mbuf, nullptr, wf20, wf21, ws + O_AFS, ws + O_AFB, nullptr, out, 384, HH);
}

// Round 9
// 353.436 us; speedup vs baseline: 2.6491x; 1.4205x over previous
//
#include <hip/hip_runtime.h>
#include <cstdint>
#include <cstddef>

namespace {

typedef unsigned short ushort_t;
typedef _Float16 half_t;
typedef __attribute__((ext_vector_type(8))) short bf8v;     // 8 bf16
typedef __attribute__((ext_vector_type(8))) _Float16 h8v;   // 8 fp16
typedef __attribute__((ext_vector_type(4))) float f4v;      // MFMA acc

constexpr float BNS = 0.99999500003749973f; // 1/sqrt(1+1e-5)

constexpr int TB = 32;
constexpr int C  = 384;
constexpr int N  = 256;
constexpr int ROWS = 868;   // 96 k + 384 v + 4 router + 384 q
constexpr int HID = 2048;
constexpr int HH  = 1024;

// ---- workspace layout (float units) ----
constexpr size_t O_A1S  = 0;         // 896 (padded)
constexpr size_t O_A1B  = 896;
constexpr size_t O_APS  = 1792;
constexpr size_t O_APB  = 2176;
constexpr size_t O_AHS  = 2560;
constexpr size_t O_AHB  = 4608;
constexpr size_t O_ADS  = 6656;
constexpr size_t O_ADB  = 7680;
constexpr size_t O_AFS  = 8704;
constexpr size_t O_AFB  = 9088;
constexpr size_t O_DWT  = 9472;      // 9216 fp32 transposed dw weights
constexpr size_t O_WPRE0 = 18688;    // 896x384 half
constexpr size_t O_WPRE1 = 190720;
constexpr size_t O_WPRJ0 = 362752;   // 384x384
constexpr size_t O_WPRJ1 = 436480;
constexpr size_t O_WF10  = 510208;   // 2048x384
constexpr size_t O_WF11  = 903424;
constexpr size_t O_WF20  = 1296640;  // 384x1024
constexpr size_t O_WF21  = 1493248;
constexpr size_t O_XTPRE = 2023168;  // half x2 [32][256][384]
constexpr size_t O_SPKB  = 5168896;  // bf16 [32][868][256]
constexpr size_t O_QT    = 8724224;  // bf16 [128][256][96]
constexpr size_t O_KT    = 10297088; // bf16 [32][256][96]
constexpr size_t O_ATTNB = 10690304; // bf16 [128][256][256]
constexpr size_t O_RES   = 14884608; // fp32 [128][256][384]
constexpr size_t O_YT    = 1689856;  // fp16 [32][256][384]
constexpr size_t O_XF0   = O_QT;     // fp16 [32][256][384] (QT dead)
constexpr size_t O_XF1   = O_ATTNB;  // fp16 (ATTNB dead)
constexpr size_t O_H     = O_RES;    // fp16 [32][256][2048] (RES dead)
constexpr size_t O_M     = 23273216; // fp16 [32][256][1024] -> ends 27467520

__device__ __forceinline__ void gload16(const void* g, void* l)
{
  __builtin_amdgcn_global_load_lds(
      (const __attribute__((address_space(1))) unsigned int*)g,
      (__attribute__((address_space(3))) unsigned int*)l, 16, 0, 0);
}

// ---------------- all affines + dw transpose in one launch ----------------
__global__ __launch_bounds__(256) void affines_all(
    const float* __restrict__ rb, const float* __restrict__ rg, const float* __restrict__ rbe,
    const float* __restrict__ eg, const float* __restrict__ eb,
    const float* __restrict__ pg, const float* __restrict__ pb, const float* __restrict__ pbe,
    const float* __restrict__ hg, const float* __restrict__ hb, const float* __restrict__ hbe,
    const float* __restrict__ dg, const float* __restrict__ db, const float* __restrict__ dbe,
    const float* __restrict__ fg, const float* __restrict__ fb, const float* __restrict__ fbe,
    const float* __restrict__ dw, float* __restrict__ ws)
{
  int u = blockIdx.x * 256 + threadIdx.x;
  if (u < 896) {
    float s, b;
    if (u < 480)      { s = 1.0f; b = 0.0f; }
    else if (u < 484) { int e = u - 480; s = rg[e] * BNS; b = rb[e] * rg[e] * BNS + rbe[e]; }
    else if (u < 868) { int j = u - 484; s = eg[j] * BNS; b = eb[j]; }
    else              { s = 0.0f; b = 0.0f; }
    ws[O_A1S + u] = s; ws[O_A1B + u] = b;
  } else if (u < 1280) {
    int j = u - 896;
    ws[O_APS + j] = pg[j] * BNS; ws[O_APB + j] = pb[j] * pg[j] * BNS + pbe[j];
  } else if (u < 3328) {
    int j = u - 1280;
    ws[O_AHS + j] = hg[j] * BNS; ws[O_AHB + j] = hb[j] * hg[j] * BNS + hbe[j];
  } else if (u < 4352) {
    int j = u - 3328;
    ws[O_ADS + j] = dg[j] * BNS; ws[O_ADB + j] = db[j] * dg[j] * BNS + dbe[j];
  } else if (u < 4736) {
    int j = u - 4352;
    ws[O_AFS + j] = fg[j] * BNS; ws[O_AFB + j] = fb[j] * fg[j] * BNS + fbe[j];
  } else if (u < 4736 + HH * 9) {
    int j = u - 4736; int ch = j / 9, i = j % 9;
    ws[O_DWT + i * HH + ch] = dw[j];
  }
}

// ---------------- all fp32 -> 2x fp16 weight splits in one launch ----------------
__global__ __launch_bounds__(256) void split_all(
    const float* __restrict__ kw, const float* __restrict__ vw,
    const float* __restrict__ rw, const float* __restrict__ ew,
    const float* __restrict__ pw, const float* __restrict__ f1w, const float* __restrict__ f2w,
    float* __restrict__ ws)
{
  int u = blockIdx.x * 256 + threadIdx.x;
  float v; size_t o0, o1; int idx;
  if (u < 344064) {
    int r = u / 384, d = u - r * 384;
    if (r < 96)       v = kw[r * 384 + d];
    else if (r < 480) v = vw[(r - 96) * 384 + d];
    else if (r < 484) v = rw[(r - 480) * 384 + d];
    else if (r < 868) v = ew[(r - 484) * 384 + d];
    else              v = 0.0f;
    o0 = O_WPRE0; o1 = O_WPRE1; idx = u;
  } else if (u < 491520) {
    idx = u - 344064; v = pw[idx]; o0 = O_WPRJ0; o1 = O_WPRJ1;
  } else if (u < 1277952) {
    idx = u - 491520; v = f1w[idx]; o0 = O_WF10; o1 = O_WF11;
  } else if (u < 1671168) {
    idx = u - 1277952; v = f2w[idx]; o0 = O_WF20; o1 = O_WF21;
  } else return;
  half_t h0 = (half_t)v;
  half_t h1 = (half_t)(v - (float)h0);
  ((half_t*)(ws + o0))[idx] = h0;
  ((half_t*)(ws + o1))[idx] = h1;
}

// ---------------- X [tb][D][N] fp32 -> XT0,XT1 [tb][N][D] fp16 (transpose + split) ----------
__global__ __launch_bounds__(256) void split_xt(
    const float* __restrict__ X, half_t* __restrict__ X0, half_t* __restrict__ X1, int D)
{
  __shared__ float tile[32][33];
  int tb = blockIdx.z, n0 = blockIdx.x * 32, d0 = blockIdx.y * 32;
  const float* src = X + (size_t)tb * D * N;
  int t = threadIdx.x;
  int nn = t & 31, ds = t >> 5;
#pragma unroll
  for (int l = 0; l < 4; ++l) {
    int dd = ds + 8 * l;
    tile[dd][nn] = src[(size_t)(d0 + dd) * N + n0 + nn];
  }
  __syncthreads();
  int dd2 = t & 31, ns = t >> 5;
#pragma unroll
  for (int l = 0; l < 4; ++l) {
    int nn2 = ns + 8 * l;
    float v = tile[dd2][nn2];
    half_t h0 = (half_t)v;
    half_t h1 = (half_t)(v - (float)h0);
    size_t o = ((size_t)tb * N + n0 + nn2) * D + d0 + dd2;
    X0[o] = h0; X1[o] = h1;
  }
}

// ======= LDS-staged split-fp16 MFMA GEMM + BN + LIF epilogue =======
// Tile: 32n x 64o x 4tt. BK=32. Double-buffered LDS via global_load_lds(16B).
// LDS rows 128B: NPROD3 X row = [op0 32k | op1 32k]; NPROD2 X row = [tt_even | tt_odd].
// XOR swizzle: LDS slot s holds data granule g = s ^ (row&7); source pre-swizzled,
// read side applies same XOR (rule #21: linear dest + inv-swz source + swz read).
// grid: x = n-tile(32), y = o-tile(64), z = b(8).
// MODE 0 (PRE): spkb bf16 [tb][868][n]   MODE 1 (PROJ): out fp32 = xin + spike
// MODE 2 (FC1): H fp16 NHWC [tb][n][O]   MODE 3 (FC2): out fp32 += spike
template<int NPROD, int MODE>
__global__ __launch_bounds__(256, 3) void sgemm_lif(
    const half_t* __restrict__ X0, const half_t* __restrict__ X1,
    const half_t* __restrict__ W0, const half_t* __restrict__ W1,
    const float* __restrict__ aS, const float* __restrict__ aB,
    const float* __restrict__ xin, void* __restrict__ dst,
    int O, int D)
{
  constexpr int XHALF = (NPROD == 3) ? 8192 : 4096;   // halves per X buffer
  __shared__ half_t smem[2 * (XHALF + 4096)];         // 48KB (NPROD3) / 32KB (NPROD2)
  half_t* xb0 = smem;
  half_t* xb1 = smem + XHALF;
  half_t* wb0 = smem + 2 * XHALF;
  half_t* wb1 = smem + 2 * XHALF + 4096;

  int b = blockIdx.z;
  int nblk = blockIdx.x * 32, o0 = blockIdx.y * 64;
  int tid = threadIdx.x, w = tid >> 6, l = tid & 63;
  int lr = l & 15, lk = l >> 4;
  int wn = w & 1, wo = w >> 1;

  auto STAGE = [&](int kt, int bi) {
    half_t* xb = bi ? xb1 : xb0;
    half_t* wb = bi ? wb1 : wb0;
    constexpr int XISS = (NPROD == 3) ? 4 : 2;
#pragma unroll
    for (int j = 0; j < XISS; ++j) {
      int gi = w * (XISS * 64) + j * 64 + l;
      int s = gi & 7, n = (gi >> 3) & 31, tz = gi >> 8;
      int g = s ^ (n & 7);
      int lk2 = g & 3;
      const half_t* src; int tt;
      if (NPROD == 3) { tt = tz; src = (g >> 2) ? X1 : X0; }
      else            { tt = tz * 2 + (g >> 2); src = X0; }
      const half_t* gp = src + ((size_t)((tt * 8 + b) * 256 + nblk + n)) * D + kt + lk2 * 8;
      gload16(gp, xb + (size_t)(w * (XISS * 64) + j * 64) * 8);
    }
#pragma unroll
    for (int j = 0; j < 2; ++j) {
      int gi = w * 128 + j * 64 + l;
      int s = gi & 7, ol = gi >> 3;
      int g = s ^ (ol & 7);
      const half_t* src = (g >> 2) ? W1 : W0;
      const half_t* gp = src + (size_t)(o0 + ol) * D + kt + (g & 3) * 8;
      gload16(gp, wb + (size_t)(w * 128 + j * 64) * 8);
    }
  };

  f4v acc[4][2] = {};   // [tt][ct]
  STAGE(0, 0);
  __syncthreads();
  int buf = 0;
  for (int kt = 0; kt < D; kt += 32) {
    if (kt + 32 < D) STAGE(kt + 32, buf ^ 1);
    half_t* xb = buf ? xb1 : xb0;
    half_t* wb = buf ? wb1 : wb0;
    h8v bb[2][2];
#pragma unroll
    for (int ct = 0; ct < 2; ++ct)
#pragma unroll
      for (int op = 0; op < 2; ++op) {
        int ol = wo * 32 + ct * 16 + lr;
        bb[ct][op] = *(const h8v*)(wb + ol * 64 + (((op << 2) | lk) ^ (ol & 7)) * 8);
      }
    h8v a[4][2];
    int nl = wn * 16 + lr;
#pragma unroll
    for (int tt = 0; tt < 4; ++tt)
#pragma unroll
      for (int op = 0; op < (NPROD == 3 ? 2 : 1); ++op) {
        int row = (NPROD == 3) ? (tt * 32 + nl) : ((tt >> 1) * 32 + nl);
        int g = (NPROD == 3) ? ((op << 2) | lk) : (((tt & 1) << 2) | lk);
        a[tt][op] = *(const h8v*)(xb + row * 64 + (g ^ (nl & 7)) * 8);
      }
#pragma unroll
    for (int tt = 0; tt < 4; ++tt)
#pragma unroll
      for (int ct = 0; ct < 2; ++ct) {
        acc[tt][ct] = __builtin_amdgcn_mfma_f32_16x16x32_f16(a[tt][0], bb[ct][0], acc[tt][ct], 0, 0, 0);
        acc[tt][ct] = __builtin_amdgcn_mfma_f32_16x16x32_f16(a[tt][0], bb[ct][1], acc[tt][ct], 0, 0, 0);
        if (NPROD == 3)
          acc[tt][ct] = __builtin_amdgcn_mfma_f32_16x16x32_f16(a[tt][1], bb[ct][0], acc[tt][ct], 0, 0, 0);
      }
    __syncthreads();
    buf ^= 1;
  }

  // BN + LIF (4 time steps in-register) -> spike bits (bit r*4+tt)
  unsigned sb_[2];
#pragma unroll
  for (int ct = 0; ct < 2; ++ct) {
    int o = o0 + wo * 32 + ct * 16 + lr;
    float s = aS[o], bbv = aB[o];
    unsigned bits = 0;
#pragma unroll
    for (int r = 0; r < 4; ++r) {
      float mem = 0.0f;
#pragma unroll
      for (int tt = 0; tt < 4; ++tt) {
        float z = acc[tt][ct][r] * s + bbv;
        mem += (z - mem) * 0.5f;
        if (mem >= 1.0f) { bits |= 1u << (r * 4 + tt); mem = 0.0f; }
      }
    }
    sb_[ct] = bits;
  }

  // LDS bounce + coalesced store, one pass per time step (smem reused)
  ushort_t* lsu = (ushort_t*)smem;   // MODE0: [64][40]; MODE2: [32][80]
  float*    lsf = (float*)smem;      // MODE1/3: [64][40]
  for (int tt = 0; tt < 4; ++tt) {
    __syncthreads();
#pragma unroll
    for (int ct = 0; ct < 2; ++ct) {
      int ol = wo * 32 + ct * 16 + lr;
#pragma unroll
      for (int r = 0; r < 4; ++r) {
        int nl2 = wn * 16 + lk * 4 + r;
        bool fire = (sb_[ct] >> (r * 4 + tt)) & 1;
        if (MODE == 0)      lsu[ol * 40 + nl2] = fire ? (ushort_t)0x3F80 : (ushort_t)0;
        else if (MODE == 2) lsu[nl2 * 80 + ol] = fire ? (ushort_t)0x3C00 : (ushort_t)0;
        else                lsf[ol * 40 + nl2] = fire ? 1.0f : 0.0f;
      }
    }
    __syncthreads();
    int tb = tt * 8 + b;
    if (MODE == 0) {
      int row = tid >> 2, cb = (tid & 3) * 8;
      if (o0 + row < O) {
        ushort_t* dp = (ushort_t*)dst + ((size_t)tb * 868 + o0 + row) * 256 + nblk + cb;
        *(uint4*)dp = *(uint4*)&lsu[row * 40 + cb];
      }
    } else if (MODE == 2) {
      int row = tid >> 3, cb = (tid & 7) * 8;
      half_t* dp = (half_t*)dst + ((size_t)tb * 256 + nblk + row) * (size_t)O + o0 + cb;
      *(uint4*)dp = *(uint4*)&lsu[row * 80 + cb];
    } else if (MODE == 1) {
      int row = tid >> 2, cb = (tid & 3) * 8;
      float* op = (float*)dst + ((size_t)tb * O + o0 + row) * 256 + nblk + cb;
      const float* xp = xin + ((size_t)tb * O + o0 + row) * 256 + nblk + cb;
#pragma unroll
      for (int j = 0; j < 2; ++j) {
        float4 sv = *(float4*)&lsf[row * 40 + cb + j * 4];
        float4 xv = *(const float4*)(xp + j * 4);
        float4 ov = {xv.x + sv.x, xv.y + sv.y, xv.z + sv.z, xv.w + sv.w};
        *(float4*)(op + j * 4) = ov;
      }
    } else {
      int row = tid >> 2, cb = (tid & 3) * 8;
      float* op = (float*)dst + ((size_t)tb * O + o0 + row) * 256 + nblk + cb;
#pragma unroll
      for (int j = 0; j < 2; ++j) {
        float4 sv = *(float4*)&lsf[row * 40 + cb + j * 4];
        float4 ov = *(float4*)(op + j * 4);
        ov.x += sv.x; ov.y += sv.y; ov.z += sv.z; ov.w += sv.w;
        *(float4*)(op + j * 4) = ov;
      }
    }
  }
}

// ---------------- transpose spikes: SPKB[tb][base+ey*96+c][n] -> dst[ey*32+tb][n][c] --------
__global__ __launch_bounds__(256) void transpose_spk(
    const ushort_t* __restrict__ SPKB, ushort_t* __restrict__ dst, int srcBase)
{
  __shared__ ushort_t tile[32][33];
  int z = blockIdx.z, tb = z & 31, ey = z >> 5;
  const ushort_t* src = SPKB + ((size_t)tb * ROWS + srcBase + ey * 96) * N;
  ushort_t* d = dst + (size_t)z * N * 96;
  int n0 = blockIdx.x * 32, c0 = blockIdx.y * 32;
  int t = threadIdx.x, nn = t & 31, cs = t >> 5;
#pragma unroll
  for (int l = 0; l < 4; ++l) {
    int cc = cs + 8 * l;
    tile[cc][nn] = src[(size_t)(c0 + cc) * N + n0 + nn];
  }
  __syncthreads();
  int cc2 = t & 31, ns = t >> 5;
#pragma unroll
  for (int l = 0; l < 4; ++l) {
    int nn2 = ns + 8 * l;
    d[(size_t)(n0 + nn2) * 96 + c0 + cc2] = tile[cc2][nn2];
  }
}

// ---------------- attn[bi][n][m] = sum_c QT[bi][n][c]*KT[tb][m][c] (bf16 MFMA, exact) -------
__global__ __launch_bounds__(256) void attn_mfma(
    const ushort_t* __restrict__ QT, const ushort_t* __restrict__ KT, ushort_t* __restrict__ ATTNB)
{
  int bi = blockIdx.y, tb = bi & 31;
  const ushort_t* q  = QT + (size_t)bi * N * 96;
  const ushort_t* kk = KT + (size_t)tb * N * 96;
  ushort_t* ob = ATTNB + (size_t)bi * N * N;
  int m0 = blockIdx.x * 128;
  int t = threadIdx.x, w = t >> 6, l = t & 63;
  int lr = l & 15, lk = l >> 4;
  int nb = w * 64;
  f4v acc[4][8] = {};
  for (int kt = 0; kt < 96; kt += 32) {
    bf8v a[4], b[8];
#pragma unroll
    for (int rt = 0; rt < 4; ++rt)
      a[rt] = *reinterpret_cast<const bf8v*>(q + (size_t)(nb + rt * 16 + lr) * 96 + kt + lk * 8);
#pragma unroll
    for (int ct = 0; ct < 8; ++ct)
      b[ct] = *reinterpret_cast<const bf8v*>(kk + (size_t)(m0 + ct * 16 + lr) * 96 + kt + lk * 8);
#pragma unroll
    for (int rt = 0; rt < 4; ++rt)
#pragma unroll
      for (int ct = 0; ct < 8; ++ct)
        acc[rt][ct] = __builtin_amdgcn_mfma_f32_16x16x32_bf16(a[rt], b[ct], acc[rt][ct], 0, 0, 0);
  }
#pragma unroll
  for (int rt = 0; rt < 4; ++rt)
#pragma unroll
    for (int ct = 0; ct < 8; ++ct)
#pragma unroll
      for (int r = 0; r < 4; ++r) {
        int n = nb + rt * 16 + lk * 4 + r;
        int m = m0 + ct * 16 + lr;
        float v = acc[rt][ct][r];
        ob[(size_t)n * N + m] = (ushort_t)(__builtin_bit_cast(unsigned, v) >> 16);
      }
}

// ---------------- res[bi][n][d] = sum_m ATTNB[bi][n][m]*v[tb][d][m] (bf16 MFMA, exact) ------
__global__ __launch_bounds__(256) void res_mfma(
    const ushort_t* __restrict__ ATTNB, const ushort_t* __restrict__ SPKB, float* __restrict__ RES)
{
  int bi = blockIdx.y, tb = bi & 31;
  const ushort_t* A = ATTNB + (size_t)bi * N * N;
  const ushort_t* V = SPKB + ((size_t)tb * ROWS + 96) * N;
  float* ob = RES + (size_t)bi * N * C;
  int d0 = blockIdx.x * 96;
  int t = threadIdx.x, w = t >> 6, l = t & 63;
  int lr = l & 15, lk = l >> 4;
  int nb = w * 64;
  f4v acc[4][6] = {};
  for (int kt = 0; kt < 256; kt += 32) {
    bf8v a[4], b[6];
#pragma unroll
    for (int rt = 0; rt < 4; ++rt)
      a[rt] = *reinterpret_cast<const bf8v*>(A + (size_t)(nb + rt * 16 + lr) * N + kt + lk * 8);
#pragma unroll
    for (int ct = 0; ct < 6; ++ct)
      b[ct] = *reinterpret_cast<const bf8v*>(V + (size_t)(d0 + ct * 16 + lr) * N + kt + lk * 8);
#pragma unroll
    for (int rt = 0; rt < 4; ++rt)
#pragma unroll
      for (int ct = 0; ct < 6; ++ct)
        acc[rt][ct] = __builtin_amdgcn_mfma_f32_16x16x32_bf16(a[rt], b[ct], acc[rt][ct], 0, 0, 0);
  }
#pragma unroll
  for (int rt = 0; rt < 4; ++rt)
#pragma unroll
    for (int ct = 0; ct < 6; ++ct)
#pragma unroll
      for (int r = 0; r < 4; ++r) {
        int n = nb + rt * 16 + lk * 4 + r;
        int d = d0 + ct * 16 + lr;
        ob[(size_t)n * C + d] = acc[rt][ct][r];
      }
}

// ---- fused RES-LIF + router-weighted sum: YT[t*8+b][n][d] = sum_e w_spk*lif(res) ----
__global__ __launch_bounds__(128) void y_lif(
    const ushort_t* __restrict__ SPKB, const float* __restrict__ RES, half_t* __restrict__ YT)
{
  int d = blockIdx.x * 128 + threadIdx.x;
  int n = blockIdx.y, b = blockIdx.z;
  float v[4] = {0.0f, 0.0f, 0.0f, 0.0f};
#pragma unroll
  for (int e = 0; e < 4; ++e) {
    float mem = 0.0f;
#pragma unroll
    for (int t = 0; t < 4; ++t) {
      float r = RES[(((size_t)(e * 32 + t * 8 + b) * 256) + n) * 384 + d];
      mem += (r - mem) * 0.5f;
      if (mem >= 1.0f) {
        mem = 0.0f;
        ushort_t wu = SPKB[((size_t)(t * 8 + b) * ROWS + 480 + e) * 256 + n];
        if (wu) v[t] += 1.0f;
      }
    }
  }
#pragma unroll
  for (int t = 0; t < 4; ++t)
    YT[((size_t)(t * 8 + b) * 256 + n) * 384 + d] = (half_t)v[t];
}

// ---------------- depthwise 3x3 NHWC fp16 + BN + LIF + gate -> M fp16 K-major --------------
__global__ __launch_bounds__(256) void dwconv_nhwc(
    const half_t* __restrict__ H, const float* __restrict__ DWT,
    const float* __restrict__ aS, const float* __restrict__ aB, half_t* __restrict__ M)
{
  int u = blockIdx.x * 256 + threadIdx.x;   // 8 * 256 * 1024
  int ch = u & 1023;
  int n = (u >> 10) & 255;
  int b = u >> 18;
  int px = n & 15, py = n >> 4;
  float w[9];
#pragma unroll
  for (int i = 0; i < 9; ++i) w[i] = DWT[i * HH + ch];
  float s = aS[ch], bb = aB[ch];
  float mem = 0.0f;
#pragma unroll
  for (int t = 0; t < 4; ++t) {
    size_t base = (size_t)(t * 8 + b) * 256;
    float acc = 0.0f;
#pragma unroll
    for (int dy = 0; dy < 3; ++dy) {
      int yy = py + dy - 1;
      if (yy < 0 || yy > 15) continue;
#pragma unroll
      for (int dx = 0; dx < 3; ++dx) {
        int xx = px + dx - 1;
        if (xx < 0 || xx > 15) continue;
        acc += (float)H[(base + yy * 16 + xx) * HID + ch] * w[dy * 3 + dx];
      }
    }
    float z = acc * s + bb;
    mem += (z - mem) * 0.5f;
    float sp = (mem >= 1.0f) ? 1.0f : 0.0f;
    mem = (sp != 0.0f) ? 0.0f : mem;
    float x2 = (float)H[(base + n) * HID + HH + ch];
    M[(base + n) * HH + ch] = (half_t)(sp * x2);
  }
}

} // namespace

extern "C" void kernel_launch(void* const* d_in, const int* in_sizes, int n_in,
                              void* d_out, int out_size, void* d_ws, size_t ws_size,
                              hipStream_t stream)
{
  const float* x         = (const float*)d_in[0];
  const float* k_w       = (const float*)d_in[2];
  const float* v_w       = (const float*)d_in[3];
  const float* router_w  = (const float*)d_in[4];
  const float* router_b  = (const float*)d_in[5];
  const float* router_g  = (const float*)d_in[6];
  const float* router_be = (const float*)d_in[7];
  const float* exp_w     = (const float*)d_in[8];
  const float* exp_g     = (const float*)d_in[9];
  const float* exp_b     = (const float*)d_in[10];
  const float* proj_w    = (const float*)d_in[11];
  const float* proj_b    = (const float*)d_in[12];
  const float* proj_g    = (const float*)d_in[13];
  const float* proj_be   = (const float*)d_in[14];
  const float* fc1_w     = (const float*)d_in[15];
  const float* fc1_b     = (const float*)d_in[16];
  const float* fc1_g     = (const float*)d_in[17];
  const float* fc1_be    = (const float*)d_in[18];
  const float* dw_w      = (const float*)d_in[19];
  const float* dw_b      = (const float*)d_in[20];
  const float* dw_g      = (const float*)d_in[21];
  const float* dw_be     = (const float*)d_in[22];
  const float* fc2_w     = (const float*)d_in[23];
  const float* fc2_b     = (const float*)d_in[24];
  const float* fc2_g     = (const float*)d_in[25];
  const float* fc2_be    = (const float*)d_in[26];

  float* ws  = (float*)d_ws;
  float* out = (float*)d_out;
  ushort_t* spkb = (ushort_t*)(ws + O_SPKB);
  ushort_t* qt   = (ushort_t*)(ws + O_QT);
  ushort_t* ktb  = (ushort_t*)(ws + O_KT);
  ushort_t* attb = (ushort_t*)(ws + O_ATTNB);
  half_t* wpre0 = (half_t*)(ws + O_WPRE0), *wpre1 = (half_t*)(ws + O_WPRE1);
  half_t* wprj0 = (half_t*)(ws + O_WPRJ0), *wprj1 = (half_t*)(ws + O_WPRJ1);
  half_t* wf10  = (half_t*)(ws + O_WF10),  *wf11  = (half_t*)(ws + O_WF11);
  half_t* wf20  = (half_t*)(ws + O_WF20),  *wf21  = (half_t*)(ws + O_WF21);
  half_t* xtpre0 = (half_t*)(ws + O_XTPRE), *xtpre1 = xtpre0 + (size_t)TB * N * C;
  half_t* yt    = (half_t*)(ws + O_YT);
  half_t* xf0   = (half_t*)(ws + O_XF0), *xf1 = (half_t*)(ws + O_XF1);
  half_t* hbuf  = (half_t*)(ws + O_H);
  half_t* mbuf  = (half_t*)(ws + O_M);
  dim3 blk(256);

  // setup: 2 launches
  affines_all<<<55, blk, 0, stream>>>(router_b, router_g, router_be, exp_g, exp_b,
                                      proj_g, proj_b, proj_be, fc1_g, fc1_b, fc1_be,
                                      dw_g, dw_b, dw_be, fc2_g, fc2_b, fc2_be, dw_w, ws);
  split_all<<<6528, blk, 0, stream>>>(k_w, v_w, router_w, exp_w, proj_w, fc1_w, fc2_w, ws);

  // pre projections: split(x) -> LDS-staged sgemm+LIF -> spkb (bf16 spikes)
  split_xt<<<dim3(8, 12, 32), blk, 0, stream>>>(x, xtpre0, xtpre1, C);
  sgemm_lif<3, 0><<<dim3(8, 14, 8), blk, 0, stream>>>(
      xtpre0, xtpre1, wpre0, wpre1, ws + O_A1S, ws + O_A1B, nullptr, spkb, 868, C);

  // attn path (exact bf16 MFMA)
  transpose_spk<<<dim3(8, 3, 32),  blk, 0, stream>>>(spkb, ktb, 0);
  transpose_spk<<<dim3(8, 3, 128), blk, 0, stream>>>(spkb, qt, 484);
  attn_mfma<<<dim3(2, 128), blk, 0, stream>>>(qt, ktb, attb);
  res_mfma<<<dim3(4, 128), blk, 0, stream>>>(attb, spkb, ws + O_RES);
  // fused RES-LIF + router sum -> YT fp16 (ints 0..4, exact)
  y_lif<<<dim3(3, 256, 8), dim3(128), 0, stream>>>(spkb, ws + O_RES, yt);

  // proj: YT fp16 exact -> sgemm+LIF -> out = x + spike
  sgemm_lif<2, 1><<<dim3(8, 6, 8), blk, 0, stream>>>(
      yt, nullptr, wprj0, wprj1, ws + O_APS, ws + O_APB, x, out, 384, C);

  // fc1: split(out) -> sgemm+LIF -> H fp16 NHWC spikes
  split_xt<<<dim3(8, 12, 32), blk, 0, stream>>>(out, xf0, xf1, C);
  sgemm_lif<3, 2><<<dim3(8, 32, 8), blk, 0, stream>>>(
      xf0, xf1, wf10, wf11, ws + O_AHS, ws + O_AHB, nullptr, hbuf, 2048, C);

  // depthwise conv + BN + LIF + gate -> M fp16 (binary, K-major)
  dwconv_nhwc<<<dim3(8192), blk, 0, stream>>>(hbuf, ws + O_DWT, ws + O_ADS, ws + O_ADB, mbuf);

  // fc2: M fp16 exact binary -> sgemm+LIF -> out += spike
  sgemm_lif<2, 3><<<dim3(8, 6, 8), blk, 0, stream>>>(
      mbuf, nullptr, wf20, wf21, ws + O_AFS, ws + O_AFB, nullptr, out, 384, HH);
}

// Round 10
// 348.460 us; speedup vs baseline: 2.6869x; 1.0143x over previous
//
#include <hip/hip_runtime.h>
#include <cstdint>
#include <cstddef>

namespace {

typedef unsigned short ushort_t;
typedef _Float16 half_t;
typedef __attribute__((ext_vector_type(8))) short bf8v;     // 8 bf16
typedef __attribute__((ext_vector_type(8))) _Float16 h8v;   // 8 fp16
typedef __attribute__((ext_vector_type(4))) _Float16 h4v;   // 4 fp16
typedef __attribute__((ext_vector_type(4))) float f4v;      // MFMA acc

constexpr float BNS = 0.99999500003749973f; // 1/sqrt(1+1e-5)

constexpr int TB = 32;
constexpr int C  = 384;
constexpr int N  = 256;
constexpr int ROWS = 868;   // 96 k + 384 v + 4 router + 384 q
constexpr int HID = 2048;
constexpr int HH  = 1024;

// ---- workspace layout (float units) ----
constexpr size_t O_A1S  = 0;         // 896 (padded)
constexpr size_t O_A1B  = 896;
constexpr size_t O_APS  = 1792;
constexpr size_t O_APB  = 2176;
constexpr size_t O_AHS  = 2560;
constexpr size_t O_AHB  = 4608;
constexpr size_t O_ADS  = 6656;
constexpr size_t O_ADB  = 7680;
constexpr size_t O_AFS  = 8704;
constexpr size_t O_AFB  = 9088;
constexpr size_t O_DWT  = 9472;      // 9216 fp32 transposed dw weights
constexpr size_t O_WPRE0 = 18688;    // 896x384 half
constexpr size_t O_WPRE1 = 190720;
constexpr size_t O_WPRJ0 = 362752;   // 384x384
constexpr size_t O_WPRJ1 = 436480;
constexpr size_t O_WF10  = 510208;   // 2048x384
constexpr size_t O_WF11  = 903424;
constexpr size_t O_WF20  = 1296640;  // 384x1024
constexpr size_t O_WF21  = 1493248;
constexpr size_t O_XTPRE = 2023168;  // half x2 [32][256][384]
constexpr size_t O_SPKB  = 5168896;  // bf16 [32][868][256]
constexpr size_t O_QT    = 8724224;  // bf16 [128][256][96]
constexpr size_t O_KT    = 10297088; // bf16 [32][256][96]
constexpr size_t O_ATTNB = 10690304; // bf16 [128][256][256]
constexpr size_t O_YT    = 1689856;  // fp16 [32][256][384]
constexpr size_t O_XF0   = O_QT;     // fp16 [32][256][384] (QT dead after attn)
constexpr size_t O_XF1   = O_ATTNB;  // fp16 (ATTNB dead after res_y)
constexpr size_t O_H     = 14884608; // fp16 [32][256][2048]
constexpr size_t O_M     = 23273216; // fp16 [32][256][1024] -> ends 27467520

__device__ __forceinline__ void gload16(const void* g, void* l)
{
  __builtin_amdgcn_global_load_lds(
      (const __attribute__((address_space(1))) unsigned int*)g,
      (__attribute__((address_space(3))) unsigned int*)l, 16, 0, 0);
}

// ---------------- all affines + dw transpose in one launch ----------------
__global__ __launch_bounds__(256) void affines_all(
    const float* __restrict__ rb, const float* __restrict__ rg, const float* __restrict__ rbe,
    const float* __restrict__ eg, const float* __restrict__ eb,
    const float* __restrict__ pg, const float* __restrict__ pb, const float* __restrict__ pbe,
    const float* __restrict__ hg, const float* __restrict__ hb, const float* __restrict__ hbe,
    const float* __restrict__ dg, const float* __restrict__ db, const float* __restrict__ dbe,
    const float* __restrict__ fg, const float* __restrict__ fb, const float* __restrict__ fbe,
    const float* __restrict__ dw, float* __restrict__ ws)
{
  int u = blockIdx.x * 256 + threadIdx.x;
  if (u < 896) {
    float s, b;
    if (u < 480)      { s = 1.0f; b = 0.0f; }
    else if (u < 484) { int e = u - 480; s = rg[e] * BNS; b = rb[e] * rg[e] * BNS + rbe[e]; }
    else if (u < 868) { int j = u - 484; s = eg[j] * BNS; b = eb[j]; }
    else              { s = 0.0f; b = 0.0f; }
    ws[O_A1S + u] = s; ws[O_A1B + u] = b;
  } else if (u < 1280) {
    int j = u - 896;
    ws[O_APS + j] = pg[j] * BNS; ws[O_APB + j] = pb[j] * pg[j] * BNS + pbe[j];
  } else if (u < 3328) {
    int j = u - 1280;
    ws[O_AHS + j] = hg[j] * BNS; ws[O_AHB + j] = hb[j] * hg[j] * BNS + hbe[j];
  } else if (u < 4352) {
    int j = u - 3328;
    ws[O_ADS + j] = dg[j] * BNS; ws[O_ADB + j] = db[j] * dg[j] * BNS + dbe[j];
  } else if (u < 4736) {
    int j = u - 4352;
    ws[O_AFS + j] = fg[j] * BNS; ws[O_AFB + j] = fb[j] * fg[j] * BNS + fbe[j];
  } else if (u < 4736 + HH * 9) {
    int j = u - 4736; int ch = j / 9, i = j % 9;
    ws[O_DWT + i * HH + ch] = dw[j];
  }
}

// ---------------- all fp32 -> 2x fp16 weight splits in one launch ----------------
__global__ __launch_bounds__(256) void split_all(
    const float* __restrict__ kw, const float* __restrict__ vw,
    const float* __restrict__ rw, const float* __restrict__ ew,
    const float* __restrict__ pw, const float* __restrict__ f1w, const float* __restrict__ f2w,
    float* __restrict__ ws)
{
  int u = blockIdx.x * 256 + threadIdx.x;
  float v; size_t o0, o1; int idx;
  if (u < 344064) {
    int r = u / 384, d = u - r * 384;
    if (r < 96)       v = kw[r * 384 + d];
    else if (r < 480) v = vw[(r - 96) * 384 + d];
    else if (r < 484) v = rw[(r - 480) * 384 + d];
    else if (r < 868) v = ew[(r - 484) * 384 + d];
    else              v = 0.0f;
    o0 = O_WPRE0; o1 = O_WPRE1; idx = u;
  } else if (u < 491520) {
    idx = u - 344064; v = pw[idx]; o0 = O_WPRJ0; o1 = O_WPRJ1;
  } else if (u < 1277952) {
    idx = u - 491520; v = f1w[idx]; o0 = O_WF10; o1 = O_WF11;
  } else if (u < 1671168) {
    idx = u - 1277952; v = f2w[idx]; o0 = O_WF20; o1 = O_WF21;
  } else return;
  half_t h0 = (half_t)v;
  half_t h1 = (half_t)(v - (float)h0);
  ((half_t*)(ws + o0))[idx] = h0;
  ((half_t*)(ws + o1))[idx] = h1;
}

// ---------------- X [tb][D][N] fp32 -> XT0,XT1 [tb][N][D] fp16 (transpose + split) ----------
__global__ __launch_bounds__(256) void split_xt(
    const float* __restrict__ X, half_t* __restrict__ X0, half_t* __restrict__ X1, int D)
{
  __shared__ float tile[32][33];
  int tb = blockIdx.z, n0 = blockIdx.x * 32, d0 = blockIdx.y * 32;
  const float* src = X + (size_t)tb * D * N;
  int t = threadIdx.x;
  int nn = t & 31, ds = t >> 5;
#pragma unroll
  for (int l = 0; l < 4; ++l) {
    int dd = ds + 8 * l;
    tile[dd][nn] = src[(size_t)(d0 + dd) * N + n0 + nn];
  }
  __syncthreads();
  int dd2 = t & 31, ns = t >> 5;
#pragma unroll
  for (int l = 0; l < 4; ++l) {
    int nn2 = ns + 8 * l;
    float v = tile[dd2][nn2];
    half_t h0 = (half_t)v;
    half_t h1 = (half_t)(v - (float)h0);
    size_t o = ((size_t)tb * N + n0 + nn2) * D + d0 + dd2;
    X0[o] = h0; X1[o] = h1;
  }
}

// ======= LDS-staged split-fp16 MFMA GEMM + BN + LIF epilogue =======
// Tile: 32n x 64o x 4tt. BK=32. Double-buffered LDS via global_load_lds(16B).
// MODE 0 (PRE): spkb bf16 [tb][868][n]   MODE 1 (PROJ): out fp32 = xin + spike, + xf split
// MODE 2 (FC1): H fp16 NHWC [tb][n][O]   MODE 3 (FC2): out fp32 += spike
template<int NPROD, int MODE>
__global__ __launch_bounds__(256, 3) void sgemm_lif(
    const half_t* __restrict__ X0, const half_t* __restrict__ X1,
    const half_t* __restrict__ W0, const half_t* __restrict__ W1,
    const float* __restrict__ aS, const float* __restrict__ aB,
    const float* __restrict__ xin, void* __restrict__ dst,
    half_t* __restrict__ xo0, half_t* __restrict__ xo1,
    int O, int D)
{
  constexpr int XHALF = (NPROD == 3) ? 8192 : 4096;   // halves per X buffer
  __shared__ half_t smem[2 * (XHALF + 4096)];         // 48KB (NPROD3) / 32KB (NPROD2)
  half_t* xb0 = smem;
  half_t* xb1 = smem + XHALF;
  half_t* wb0 = smem + 2 * XHALF;
  half_t* wb1 = smem + 2 * XHALF + 4096;

  int b = blockIdx.z;
  int nblk = blockIdx.x * 32, o0 = blockIdx.y * 64;
  int tid = threadIdx.x, w = tid >> 6, l = tid & 63;
  int lr = l & 15, lk = l >> 4;
  int wn = w & 1, wo = w >> 1;

  auto STAGE = [&](int kt, int bi) {
    half_t* xb = bi ? xb1 : xb0;
    half_t* wb = bi ? wb1 : wb0;
    constexpr int XISS = (NPROD == 3) ? 4 : 2;
#pragma unroll
    for (int j = 0; j < XISS; ++j) {
      int gi = w * (XISS * 64) + j * 64 + l;
      int s = gi & 7, n = (gi >> 3) & 31, tz = gi >> 8;
      int g = s ^ (n & 7);
      int lk2 = g & 3;
      const half_t* src; int tt;
      if (NPROD == 3) { tt = tz; src = (g >> 2) ? X1 : X0; }
      else            { tt = tz * 2 + (g >> 2); src = X0; }
      const half_t* gp = src + ((size_t)((tt * 8 + b) * 256 + nblk + n)) * D + kt + lk2 * 8;
      gload16(gp, xb + (size_t)(w * (XISS * 64) + j * 64) * 8);
    }
#pragma unroll
    for (int j = 0; j < 2; ++j) {
      int gi = w * 128 + j * 64 + l;
      int s = gi & 7, ol = gi >> 3;
      int g = s ^ (ol & 7);
      const half_t* src = (g >> 2) ? W1 : W0;
      const half_t* gp = src + (size_t)(o0 + ol) * D + kt + (g & 3) * 8;
      gload16(gp, wb + (size_t)(w * 128 + j * 64) * 8);
    }
  };

  f4v acc[4][2] = {};   // [tt][ct]
  STAGE(0, 0);
  __syncthreads();
  int buf = 0;
  for (int kt = 0; kt < D; kt += 32) {
    if (kt + 32 < D) STAGE(kt + 32, buf ^ 1);
    half_t* xb = buf ? xb1 : xb0;
    half_t* wb = buf ? wb1 : wb0;
    h8v bb[2][2];
#pragma unroll
    for (int ct = 0; ct < 2; ++ct)
#pragma unroll
      for (int op = 0; op < 2; ++op) {
        int ol = wo * 32 + ct * 16 + lr;
        bb[ct][op] = *(const h8v*)(wb + ol * 64 + (((op << 2) | lk) ^ (ol & 7)) * 8);
      }
    h8v a[4][2];
    int nl = wn * 16 + lr;
#pragma unroll
    for (int tt = 0; tt < 4; ++tt)
#pragma unroll
      for (int op = 0; op < (NPROD == 3 ? 2 : 1); ++op) {
        int row = (NPROD == 3) ? (tt * 32 + nl) : ((tt >> 1) * 32 + nl);
        int g = (NPROD == 3) ? ((op << 2) | lk) : (((tt & 1) << 2) | lk);
        a[tt][op] = *(const h8v*)(xb + row * 64 + (g ^ (nl & 7)) * 8);
      }
#pragma unroll
    for (int tt = 0; tt < 4; ++tt)
#pragma unroll
      for (int ct = 0; ct < 2; ++ct) {
        acc[tt][ct] = __builtin_amdgcn_mfma_f32_16x16x32_f16(a[tt][0], bb[ct][0], acc[tt][ct], 0, 0, 0);
        acc[tt][ct] = __builtin_amdgcn_mfma_f32_16x16x32_f16(a[tt][0], bb[ct][1], acc[tt][ct], 0, 0, 0);
        if (NPROD == 3)
          acc[tt][ct] = __builtin_amdgcn_mfma_f32_16x16x32_f16(a[tt][1], bb[ct][0], acc[tt][ct], 0, 0, 0);
      }
    __syncthreads();
    buf ^= 1;
  }

  // BN + LIF (4 time steps in-register) -> spike bits (bit r*4+tt)
  unsigned sb_[2];
#pragma unroll
  for (int ct = 0; ct < 2; ++ct) {
    int o = o0 + wo * 32 + ct * 16 + lr;
    float s = aS[o], bbv = aB[o];
    unsigned bits = 0;
#pragma unroll
    for (int r = 0; r < 4; ++r) {
      float mem = 0.0f;
#pragma unroll
      for (int tt = 0; tt < 4; ++tt) {
        float z = acc[tt][ct][r] * s + bbv;
        mem += (z - mem) * 0.5f;
        if (mem >= 1.0f) { bits |= 1u << (r * 4 + tt); mem = 0.0f; }
      }
    }
    sb_[ct] = bits;
  }

  // LDS bounce + coalesced store, one pass per time step (smem reused)
  ushort_t* lsu = (ushort_t*)smem;   // MODE0: [64][40]; MODE2: [32][80]
  float*    lsf = (float*)smem;      // MODE1/3: [64][40]
  float*    lsx = (float*)smem + 64 * 40;  // MODE1: [32n][68] transposed sum
  for (int tt = 0; tt < 4; ++tt) {
    __syncthreads();
#pragma unroll
    for (int ct = 0; ct < 2; ++ct) {
      int ol = wo * 32 + ct * 16 + lr;
#pragma unroll
      for (int r = 0; r < 4; ++r) {
        int nl2 = wn * 16 + lk * 4 + r;
        bool fire = (sb_[ct] >> (r * 4 + tt)) & 1;
        if (MODE == 0)      lsu[ol * 40 + nl2] = fire ? (ushort_t)0x3F80 : (ushort_t)0;
        else if (MODE == 2) lsu[nl2 * 80 + ol] = fire ? (ushort_t)0x3C00 : (ushort_t)0;
        else                lsf[ol * 40 + nl2] = fire ? 1.0f : 0.0f;
      }
    }
    __syncthreads();
    int tb = tt * 8 + b;
    if (MODE == 0) {
      int row = tid >> 2, cb = (tid & 3) * 8;
      if (o0 + row < O) {
        ushort_t* dp = (ushort_t*)dst + ((size_t)tb * 868 + o0 + row) * 256 + nblk + cb;
        *(uint4*)dp = *(uint4*)&lsu[row * 40 + cb];
      }
    } else if (MODE == 2) {
      int row = tid >> 3, cb = (tid & 7) * 8;
      half_t* dp = (half_t*)dst + ((size_t)tb * 256 + nblk + row) * (size_t)O + o0 + cb;
      *(uint4*)dp = *(uint4*)&lsu[row * 80 + cb];
    } else if (MODE == 1) {
      int row = tid >> 2, cb = (tid & 3) * 8;
      float* op = (float*)dst + ((size_t)tb * O + o0 + row) * 256 + nblk + cb;
      const float* xp = xin + ((size_t)tb * O + o0 + row) * 256 + nblk + cb;
#pragma unroll
      for (int j = 0; j < 2; ++j) {
        float4 sv = *(float4*)&lsf[row * 40 + cb + j * 4];
        float4 xv = *(const float4*)(xp + j * 4);
        float4 ov = {xv.x + sv.x, xv.y + sv.y, xv.z + sv.z, xv.w + sv.w};
        *(float4*)(op + j * 4) = ov;
        lsx[(cb + j * 4 + 0) * 68 + row] = ov.x;
        lsx[(cb + j * 4 + 1) * 68 + row] = ov.y;
        lsx[(cb + j * 4 + 2) * 68 + row] = ov.z;
        lsx[(cb + j * 4 + 3) * 68 + row] = ov.w;
      }
      __syncthreads();
      // split-write xf: [tb][n][384] K-major halves
      int rn = tid >> 3, co = (tid & 7) * 8;
      h8v h0, h1;
#pragma unroll
      for (int j = 0; j < 8; ++j) {
        float v = lsx[rn * 68 + co + j];
        half_t a0 = (half_t)v;
        h0[j] = a0;
        h1[j] = (half_t)(v - (float)a0);
      }
      size_t xo = ((size_t)tb * 256 + nblk + rn) * 384 + o0 + co;
      *(h8v*)(xo0 + xo) = h0;
      *(h8v*)(xo1 + xo) = h1;
    } else {
      int row = tid >> 2, cb = (tid & 3) * 8;
      float* op = (float*)dst + ((size_t)tb * O + o0 + row) * 256 + nblk + cb;
#pragma unroll
      for (int j = 0; j < 2; ++j) {
        float4 sv = *(float4*)&lsf[row * 40 + cb + j * 4];
        float4 ov = *(float4*)(op + j * 4);
        ov.x += sv.x; ov.y += sv.y; ov.z += sv.z; ov.w += sv.w;
        *(float4*)(op + j * 4) = ov;
      }
    }
  }
}

// ---------------- transpose spikes: SPKB[tb][base+ey*96+c][n] -> dst[ey*32+tb][n][c] --------
__global__ __launch_bounds__(256) void transpose_spk(
    const ushort_t* __restrict__ SPKB, ushort_t* __restrict__ dst, int srcBase)
{
  __shared__ ushort_t tile[32][33];
  int z = blockIdx.z, tb = z & 31, ey = z >> 5;
  const ushort_t* src = SPKB + ((size_t)tb * ROWS + srcBase + ey * 96) * N;
  ushort_t* d = dst + (size_t)z * N * 96;
  int n0 = blockIdx.x * 32, c0 = blockIdx.y * 32;
  int t = threadIdx.x, nn = t & 31, cs = t >> 5;
#pragma unroll
  for (int l = 0; l < 4; ++l) {
    int cc = cs + 8 * l;
    tile[cc][nn] = src[(size_t)(c0 + cc) * N + n0 + nn];
  }
  __syncthreads();
  int cc2 = t & 31, ns = t >> 5;
#pragma unroll
  for (int l = 0; l < 4; ++l) {
    int nn2 = ns + 8 * l;
    d[(size_t)(n0 + nn2) * 96 + c0 + cc2] = tile[cc2][nn2];
  }
}

// ---------------- attn[bi][n][m] = sum_c QT[bi][n][c]*KT[tb][m][c] (bf16 MFMA, exact) -------
__global__ __launch_bounds__(256) void attn_mfma(
    const ushort_t* __restrict__ QT, const ushort_t* __restrict__ KT, ushort_t* __restrict__ ATTNB)
{
  int bi = blockIdx.y, tb = bi & 31;
  const ushort_t* q  = QT + (size_t)bi * N * 96;
  const ushort_t* kk = KT + (size_t)tb * N * 96;
  ushort_t* ob = ATTNB + (size_t)bi * N * N;
  int m0 = blockIdx.x * 128;
  int t = threadIdx.x, w = t >> 6, l = t & 63;
  int lr = l & 15, lk = l >> 4;
  int nb = w * 64;
  f4v acc[4][8] = {};
  for (int kt = 0; kt < 96; kt += 32) {
    bf8v a[4], b[8];
#pragma unroll
    for (int rt = 0; rt < 4; ++rt)
      a[rt] = *reinterpret_cast<const bf8v*>(q + (size_t)(nb + rt * 16 + lr) * 96 + kt + lk * 8);
#pragma unroll
    for (int ct = 0; ct < 8; ++ct)
      b[ct] = *reinterpret_cast<const bf8v*>(kk + (size_t)(m0 + ct * 16 + lr) * 96 + kt + lk * 8);
#pragma unroll
    for (int rt = 0; rt < 4; ++rt)
#pragma unroll
      for (int ct = 0; ct < 8; ++ct)
        acc[rt][ct] = __builtin_amdgcn_mfma_f32_16x16x32_bf16(a[rt], b[ct], acc[rt][ct], 0, 0, 0);
  }
#pragma unroll
  for (int rt = 0; rt < 4; ++rt)
#pragma unroll
    for (int ct = 0; ct < 8; ++ct)
#pragma unroll
      for (int r = 0; r < 4; ++r) {
        int n = nb + rt * 16 + lk * 4 + r;
        int m = m0 + ct * 16 + lr;
        float v = acc[rt][ct][r];
        ob[(size_t)n * N + m] = (ushort_t)(__builtin_bit_cast(unsigned, v) >> 16);
      }
}

// ======= fused res GEMM + RES-LIF + router-weighted expert sum -> YT fp16 =======
// grid (12 d-tiles of 32, 8 n-tiles of 32, 8 b); 4 waves, wave w = expert e.
// res[e,t][n][d] = sum_m ATTNB[e*32+t*8+b][n][m] * v_spk[t*8+b][d][m]  (exact ints)
// LIF over t in-register (exact), gate by router spike w[e,t,n], sum over e via LDS.
__global__ __launch_bounds__(256) void res_y(
    const ushort_t* __restrict__ ATTNB, const ushort_t* __restrict__ SPKB,
    half_t* __restrict__ YT)
{
  __shared__ ushort_t wlds[512];      // [e][t][32n] router spikes
  __shared__ half_t wt[4][32][36];    // per-expert contribution tile
  int b = blockIdx.z;
  int n0 = blockIdx.y * 32;
  int d0 = blockIdx.x * 32;
  int tid = threadIdx.x, e = tid >> 6, l = tid & 63;
  int lr = l & 15, lk = l >> 4;
  for (int j = tid; j < 512; j += 256) {
    int ee = j >> 7, t = (j >> 5) & 3, nl = j & 31;
    wlds[j] = SPKB[((size_t)((t * 8 + b) * ROWS) + 480 + ee) * 256 + n0 + nl];
  }
  __syncthreads();
  f4v acc[4][2][2] = {};   // [t][rt][ct]
#pragma unroll
  for (int t = 0; t < 4; ++t) {
    const ushort_t* A = ATTNB + (size_t)(e * 32 + t * 8 + b) * 65536;
    const ushort_t* V = SPKB + ((size_t)((t * 8 + b) * ROWS) + 96) * 256;
#pragma unroll
    for (int kt = 0; kt < 256; kt += 32) {
      bf8v a[2], bb[2];
#pragma unroll
      for (int rt = 0; rt < 2; ++rt)
        a[rt] = *(const bf8v*)(A + (size_t)(n0 + rt * 16 + lr) * 256 + kt + lk * 8);
#pragma unroll
      for (int ct = 0; ct < 2; ++ct)
        bb[ct] = *(const bf8v*)(V + (size_t)(d0 + ct * 16 + lr) * 256 + kt + lk * 8);
#pragma unroll
      for (int rt = 0; rt < 2; ++rt)
#pragma unroll
        for (int ct = 0; ct < 2; ++ct)
          acc[t][rt][ct] = __builtin_amdgcn_mfma_f32_16x16x32_bf16(a[rt], bb[ct], acc[t][rt][ct], 0, 0, 0);
    }
  }
  // LIF over t (exact int dynamics) + router gate -> bits (bit t*4+r)
  unsigned sb2[2][2] = {{0, 0}, {0, 0}};
#pragma unroll
  for (int rt = 0; rt < 2; ++rt)
#pragma unroll
    for (int ct = 0; ct < 2; ++ct)
#pragma unroll
      for (int r = 0; r < 4; ++r) {
        int nl = rt * 16 + lk * 4 + r;
        float mem = 0.0f;
#pragma unroll
        for (int t = 0; t < 4; ++t) {
          float v = acc[t][rt][ct][r];
          mem += (v - mem) * 0.5f;
          if (mem >= 1.0f) {
            mem = 0.0f;
            if (wlds[(e * 4 + t) * 32 + nl]) sb2[rt][ct] |= 1u << (t * 4 + r);
          }
        }
      }
  // per-t: each wave deposits its expert's 0/1, readers sum 4 and write YT
  for (int t = 0; t < 4; ++t) {
    __syncthreads();
#pragma unroll
    for (int rt = 0; rt < 2; ++rt)
#pragma unroll
      for (int ct = 0; ct < 2; ++ct)
#pragma unroll
        for (int r = 0; r < 4; ++r) {
          int nl = rt * 16 + lk * 4 + r;
          int dl = ct * 16 + lr;
          wt[e][nl][dl] = ((sb2[rt][ct] >> (t * 4 + r)) & 1) ? (half_t)1.0f : (half_t)0.0f;
        }
    __syncthreads();
    int row = tid >> 3, cb = (tid & 7) * 4;
    h4v o4;
#pragma unroll
    for (int j = 0; j < 4; ++j) {
      float s = (float)wt[0][row][cb + j] + (float)wt[1][row][cb + j]
              + (float)wt[2][row][cb + j] + (float)wt[3][row][cb + j];
      o4[j] = (half_t)s;
    }
    *(h4v*)(YT + ((size_t)((t * 8 + b) * 256) + n0 + row) * 384 + d0 + cb) = o4;
  }
}

// ---------------- depthwise 3x3 NHWC fp16 + BN + LIF + gate -> M fp16 K-major --------------
__global__ __launch_bounds__(256) void dwconv_nhwc(
    const half_t* __restrict__ H, const float* __restrict__ DWT,
    const float* __restrict__ aS, const float* __restrict__ aB, half_t* __restrict__ M)
{
  int u = blockIdx.x * 256 + threadIdx.x;   // 8 * 256 * 1024
  int ch = u & 1023;
  int n = (u >> 10) & 255;
  int b = u >> 18;
  int px = n & 15, py = n >> 4;
  float w[9];
#pragma unroll
  for (int i = 0; i < 9; ++i) w[i] = DWT[i * HH + ch];
  float s = aS[ch], bb = aB[ch];
  float mem = 0.0f;
#pragma unroll
  for (int t = 0; t < 4; ++t) {
    size_t base = (size_t)(t * 8 + b) * 256;
    float acc = 0.0f;
#pragma unroll
    for (int dy = 0; dy < 3; ++dy) {
      int yy = py + dy - 1;
      if (yy < 0 || yy > 15) continue;
#pragma unroll
      for (int dx = 0; dx < 3; ++dx) {
        int xx = px + dx - 1;
        if (xx < 0 || xx > 15) continue;
        acc += (float)H[(base + yy * 16 + xx) * HID + ch] * w[dy * 3 + dx];
      }
    }
    float z = acc * s + bb;
    mem += (z - mem) * 0.5f;
    float sp = (mem >= 1.0f) ? 1.0f : 0.0f;
    mem = (sp != 0.0f) ? 0.0f : mem;
    float x2 = (float)H[(base + n) * HID + HH + ch];
    M[(base + n) * HH + ch] = (half_t)(sp * x2);
  }
}

} // namespace

extern "C" void kernel_launch(void* const* d_in, const int* in_sizes, int n_in,
                              void* d_out, int out_size, void* d_ws, size_t ws_size,
                              hipStream_t stream)
{
  const float* x         = (const float*)d_in[0];
  const float* k_w       = (const float*)d_in[2];
  const float* v_w       = (const float*)d_in[3];
  const float* router_w  = (const float*)d_in[4];
  const float* router_b  = (const float*)d_in[5];
  const float* router_g  = (const float*)d_in[6];
  const float* router_be = (const float*)d_in[7];
  const float* exp_w     = (const float*)d_in[8];
  const float* exp_g     = (const float*)d_in[9];
  const float* exp_b     = (const float*)d_in[10];
  const float* proj_w    = (const float*)d_in[11];
  const float* proj_b    = (const float*)d_in[12];
  const float* proj_g    = (const float*)d_in[13];
  const float* proj_be   = (const float*)d_in[14];
  const float* fc1_w     = (const float*)d_in[15];
  const float* fc1_b     = (const float*)d_in[16];
  const float* fc1_g     = (const float*)d_in[17];
  const float* fc1_be    = (const float*)d_in[18];
  const float* dw_w      = (const float*)d_in[19];
  const float* dw_b      = (const float*)d_in[20];
  const float* dw_g      = (const float*)d_in[21];
  const float* dw_be     = (const float*)d_in[22];
  const float* fc2_w     = (const float*)d_in[23];
  const float* fc2_b     = (const float*)d_in[24];
  const float* fc2_g     = (const float*)d_in[25];
  const float* fc2_be    = (const float*)d_in[26];

  float* ws  = (float*)d_ws;
  float* out = (float*)d_out;
  ushort_t* spkb = (ushort_t*)(ws + O_SPKB);
  ushort_t* qt   = (ushort_t*)(ws + O_QT);
  ushort_t* ktb  = (ushort_t*)(ws + O_KT);
  ushort_t* attb = (ushort_t*)(ws + O_ATTNB);
  half_t* wpre0 = (half_t*)(ws + O_WPRE0), *wpre1 = (half_t*)(ws + O_WPRE1);
  half_t* wprj0 = (half_t*)(ws + O_WPRJ0), *wprj1 = (half_t*)(ws + O_WPRJ1);
  half_t* wf10  = (half_t*)(ws + O_WF10),  *wf11  = (half_t*)(ws + O_WF11);
  half_t* wf20  = (half_t*)(ws + O_WF20),  *wf21  = (half_t*)(ws + O_WF21);
  half_t* xtpre0 = (half_t*)(ws + O_XTPRE), *xtpre1 = xtpre0 + (size_t)TB * N * C;
  half_t* yt    = (half_t*)(ws + O_YT);
  half_t* xf0   = (half_t*)(ws + O_XF0), *xf1 = (half_t*)(ws + O_XF1);
  half_t* hbuf  = (half_t*)(ws + O_H);
  half_t* mbuf  = (half_t*)(ws + O_M);
  dim3 blk(256);

  // setup: 2 launches
  affines_all<<<55, blk, 0, stream>>>(router_b, router_g, router_be, exp_g, exp_b,
                                      proj_g, proj_b, proj_be, fc1_g, fc1_b, fc1_be,
                                      dw_g, dw_b, dw_be, fc2_g, fc2_b, fc2_be, dw_w, ws);
  split_all<<<6528, blk, 0, stream>>>(k_w, v_w, router_w, exp_w, proj_w, fc1_w, fc2_w, ws);

  // pre projections: split(x) -> LDS-staged sgemm+LIF -> spkb (bf16 spikes)
  split_xt<<<dim3(8, 12, 32), blk, 0, stream>>>(x, xtpre0, xtpre1, C);
  sgemm_lif<3, 0><<<dim3(8, 14, 8), blk, 0, stream>>>(
      xtpre0, xtpre1, wpre0, wpre1, ws + O_A1S, ws + O_A1B, nullptr, spkb,
      nullptr, nullptr, 868, C);

  // attn path (exact bf16 MFMA)
  transpose_spk<<<dim3(8, 3, 32),  blk, 0, stream>>>(spkb, ktb, 0);
  transpose_spk<<<dim3(8, 3, 128), blk, 0, stream>>>(spkb, qt, 484);
  attn_mfma<<<dim3(2, 128), blk, 0, stream>>>(qt, ktb, attb);
  // fused res GEMM + RES-LIF + router sum -> YT fp16 (ints 0..4, exact)
  res_y<<<dim3(12, 8, 8), blk, 0, stream>>>(attb, spkb, yt);

  // proj: YT fp16 exact -> sgemm+LIF -> out = x + spike, also emits xf0/xf1 split
  sgemm_lif<2, 1><<<dim3(8, 6, 8), blk, 0, stream>>>(
      yt, nullptr, wprj0, wprj1, ws + O_APS, ws + O_APB, x, out, xf0, xf1, 384, C);

  // fc1: xf (from proj epilogue) -> sgemm+LIF -> H fp16 NHWC spikes
  sgemm_lif<3, 2><<<dim3(8, 32, 8), blk, 0, stream>>>(
      xf0, xf1, wf10, wf11, ws + O_AHS, ws + O_AHB, nullptr, hbuf,
      nullptr, nullptr, 2048, C);

  // depthwise conv + BN + LIF + gate -> M fp16 (binary, K-major)
  dwconv_nhwc<<<dim3(8192), blk, 0, stream>>>(hbuf, ws + O_DWT, ws + O_ADS, ws + O_ADB, mbuf);

  // fc2: M fp16 exact binary -> sgemm+LIF -> out += spike
  sgemm_lif<2, 3><<<dim3(8, 6, 8), blk, 0, stream>>>(
      mbuf, nullptr, wf20, wf21, ws + O_AFS, ws + O_AFB, nullptr, out,
      nullptr, nullptr, 384, HH);
}